// Round 11
// baseline (6475.990 us; speedup 1.0000x reference)
//
#include <hip/hip_runtime.h>
#include <hip/hip_bf16.h>
#include <stdint.h>

// Seq2Seq w/ attention, MI355X. R11 = R10 + 1-line fix:
//  __syncthreads() before k1's cbuf store. R8-R10's FAIL root cause: gates narrowed
//  to wave 0 (tid<64) but the c_e handoff store stayed tid<128 with no barrier ->
//  wave 1 stored stale s_c (c_511 not c_512) for batches 8-15 of each group.
//  k1 = tagged h-exchange (u64 {hi_a,hi_b,lo_a15,lo_b15,tag2}, 1 IF RT/step).
//  k2 = R7's PASS-verified flag kernel; preloop unpacks k1's pair format.

#define HID 512
#define NBAT 64
#define SEQE 512
#define SEQD 128
#define NGRP 4
#define GBAT 16
#define GBLK 64
#define NH 8
#define SCALE 0.04419417382415922f
#define FLS 16

typedef __attribute__((ext_vector_type(8))) short bf16x8;
typedef __attribute__((ext_vector_type(4))) float f32x4;
#define MFMA_B16 __builtin_amdgcn_mfma_f32_16x16x32_bf16

static constexpr size_t OFF_G   = 0;
static constexpr size_t OFF_NM  = OFF_G  + (size_t)HID*HID*4;
static constexpr size_t OFF_M0  = OFF_NM + (size_t)HID*HID*4;
static constexpr size_t OFF_N0  = OFF_M0 + 2048;
static constexpr size_t OFF_WQB = OFF_N0 + 2048;
static constexpr size_t OFF_SC  = OFF_WQB + 2048;                   // Swg, Swb, bqbk
static constexpr size_t OFF_HB  = OFF_SC + 256;                     // h 3-slot [3][B][H]*4B
static constexpr size_t OFF_CB  = OFF_HB + (size_t)3*NBAT*HID*4;    // c handoff f32
static constexpr size_t OFF_EBP = OFF_CB + (size_t)NBAT*HID*4;      // PV partials [B][4][H] f32
static constexpr size_t OFF_MD  = OFF_EBP + (size_t)NBAT*4*HID*4;   // den partials [B][4]
static constexpr size_t OFF_KB  = OFF_MD + (size_t)NBAT*4*4;        // kb [B][Se] f32
static constexpr size_t OFF_FLG = OFF_KB + (size_t)NBAT*SEQE*4;     // 3 sets x NGRP x 64 flags
static constexpr size_t OFF_XPK = OFF_FLG + (size_t)3*NGRP*GBLK*FLS*4; // [B] u64 {o,epoch}
static constexpr size_t OFF_BFK = ((OFF_XPK + 512 + 255) & ~(size_t)255);
static constexpr size_t OFF_BFV = OFF_BFK + (size_t)16*32*64*8*2;   // 512KB each
static constexpr size_t OFF_EO  = OFF_BFV + (size_t)16*32*64*8*2;   // eo then K~ [B][Se][H] bf16
static constexpr size_t OFF_VT  = OFF_EO + (size_t)NBAT*SEQE*HID*2; // V~t [B][H][Se] bf16

__device__ __forceinline__ float bf2f(uint32_t u) {
  union { float f; uint32_t i; } x; x.i = u << 16; return x.f;
}
__device__ __forceinline__ unsigned short bfbits(float f) {
  __hip_bfloat16 h = __float2bfloat16(f);
  return *(unsigned short*)&h;
}
__device__ __forceinline__ uint32_t splitbf(float f) {
  unsigned short hi = bfbits(f);
  union { uint32_t u; float ff; } c; c.u = (uint32_t)hi << 16;
  unsigned short lo = bfbits(f - c.ff);
  return (uint32_t)hi | ((uint32_t)lo << 16);
}
__device__ __forceinline__ float sigm(float x) { return 1.f / (1.f + __expf(-x)); }

__device__ __forceinline__ void stg(float* p, float v) {
  __hip_atomic_store(p, v, __ATOMIC_RELAXED, __HIP_MEMORY_SCOPE_AGENT);
}
__device__ __forceinline__ void stgu(uint32_t* p, uint32_t v) {
  __hip_atomic_store(p, v, __ATOMIC_RELAXED, __HIP_MEMORY_SCOPE_AGENT);
}
__device__ __forceinline__ void stgi(int* p, int v) {
  __hip_atomic_store(p, v, __ATOMIC_RELAXED, __HIP_MEMORY_SCOPE_AGENT);
}
__device__ __forceinline__ void stg64(unsigned long long* p, unsigned long long v) {
  __hip_atomic_store(p, v, __ATOMIC_RELAXED, __HIP_MEMORY_SCOPE_AGENT);
}
__device__ __forceinline__ float ldg1(const float* p) {
  return __hip_atomic_load((float*)p, __ATOMIC_RELAXED, __HIP_MEMORY_SCOPE_AGENT);
}
__device__ __forceinline__ int ldgi(const int* p) {
  return __hip_atomic_load((int*)p, __ATOMIC_RELAXED, __HIP_MEMORY_SCOPE_AGENT);
}
__device__ __forceinline__ unsigned long long ldg8(const void* p) {
  return __hip_atomic_load((unsigned long long*)p, __ATOMIC_RELAXED, __HIP_MEMORY_SCOPE_AGENT);
}

#define POLL_GE(addr, thr) \
  while (ldgi(addr) < (thr)) __builtin_amdgcn_s_sleep(1);
#define CFENCE() __asm__ __volatile__("" ::: "memory")

__global__ __launch_bounds__(256) void k0_prep(
    const float* __restrict__ aiw, const float* __restrict__ aib,
    const float* __restrict__ aow, const float* __restrict__ aob,
    const float* __restrict__ outw, const float* __restrict__ lng,
    const float* __restrict__ lnb, char* __restrict__ ws) {
  float* Gm = (float*)(ws + OFF_G);
  float* Nm = (float*)(ws + OFF_NM);
  float* m0 = (float*)(ws + OFF_M0);
  float* n0 = (float*)(ws + OFF_N0);
  float* wqb = (float*)(ws + OFF_WQB);
  float* sc = (float*)(ws + OFF_SC);
  const int blk = blockIdx.x, tid = threadIdx.x;
  if (blk == 512) {
    uint32_t* hb = (uint32_t*)(ws + OFF_HB);
    int* fl = (int*)(ws + OFF_FLG);
    unsigned long long* xpk = (unsigned long long*)(ws + OFF_XPK);
    for (int i = tid; i < 3*NBAT*HID; i += 256) hb[i] = 0u;          // all slots: h0/tag0
    for (int i = tid; i < 3*NGRP*GBLK*FLS; i += 256) {
      int set = i / (GBLK*FLS);
      fl[i] = (set >= NGRP && set < 2*NGRP) ? -1 : 0;                // k2 h-flags start -1
    }
    for (int i = tid; i < NBAT; i += 256) xpk[i] = 0ull;
    for (int l = tid; l < HID; l += 256) {
      float s = 0.f;
      for (int i = 0; i < HID; i++) s += aib[i] * aiw[(size_t)(HID + i)*HID + l];
      m0[l] = s;  // Wk^T bq
    }
    for (int l = tid; l < HID; l += 256) {
      float s = 0.f;
      for (int i = 0; i < HID; i++) s += aiw[(size_t)i*HID + l] * aib[HID + i];
      wqb[l] = s;  // Wq^T bk
    }
    for (int j = tid; j < HID; j += 256) {
      float s = aob[j];
      for (int i = 0; i < HID; i++) s += aow[(size_t)j*HID + i] * aib[2*HID + i];
      n0[j] = s;  // aow*bv + aob
    }
    __shared__ float red[256];
    float a = 0.f, b = 0.f, d = 0.f;
    for (int l = tid; l < HID; l += 256) {
      a += outw[l]*lng[l]; b += outw[l]*lnb[l]; d += aib[l]*aib[HID + l];
    }
    red[tid] = a; __syncthreads();
    for (int st = 128; st; st >>= 1) { if (tid < st) red[tid] += red[tid + st]; __syncthreads(); }
    if (tid == 0) sc[0] = red[0];
    __syncthreads();
    red[tid] = b; __syncthreads();
    for (int st = 128; st; st >>= 1) { if (tid < st) red[tid] += red[tid + st]; __syncthreads(); }
    if (tid == 0) sc[1] = red[0];
    __syncthreads();
    red[tid] = d; __syncthreads();
    for (int st = 128; st; st >>= 1) { if (tid < st) red[tid] += red[tid + st]; __syncthreads(); }
    if (tid == 0) sc[2] = red[0];  // bq.bk
    return;
  }
  const bool isG = blk < 256;
  const int tb = isG ? blk : blk - 256;
  const int r0 = (tb >> 4) * 32, c0 = (tb & 15) * 32;
  __shared__ float sa[32][33], sb[32][33];
  float acc[4] = {0.f, 0.f, 0.f, 0.f};
  const int tr = tid >> 3, tc = (tid & 7) * 4;
  for (int i0 = 0; i0 < HID; i0 += 32) {
    __syncthreads();
    if (isG) {  // Gm[l][k] = sum_i Wk[i][l]*Wq[i][k]
      for (int j = 0; j < 4; j++) sa[tr][tc + j] = aiw[(size_t)(HID + i0 + tr)*HID + r0 + tc + j];
      for (int j = 0; j < 4; j++) sb[tr][tc + j] = aiw[(size_t)(i0 + tr)*HID + c0 + tc + j];
    } else {    // N[j][l] = sum_i aow[j][i]*Wv[i][l]
      for (int j = 0; j < 4; j++) sa[tr][tc + j] = aow[(size_t)(r0 + tr)*HID + i0 + tc + j];
      for (int j = 0; j < 4; j++) sb[tr][tc + j] = aiw[(size_t)(2*HID + i0 + tr)*HID + c0 + tc + j];
    }
    __syncthreads();
    if (isG) {
      for (int i = 0; i < 32; i++) {
        float a = sa[i][tr];
        for (int j = 0; j < 4; j++) acc[j] += a * sb[i][tc + j];
      }
    } else {
      for (int i = 0; i < 32; i++) {
        float a = sa[tr][i];
        for (int j = 0; j < 4; j++) acc[j] += a * sb[i][tc + j];
      }
    }
  }
  float* dst = isG ? Gm : Nm;
  for (int j = 0; j < 4; j++) dst[(size_t)(r0 + tr)*HID + c0 + tc + j] = acc[j];
}

// B-fragments (verified)
__global__ __launch_bounds__(256) void k0b_frag(char* __restrict__ ws) {
  const float* Gm = (const float*)(ws + OFF_G);
  const float* Nm = (const float*)(ws + OFF_NM);
  unsigned short* Bfk = (unsigned short*)(ws + OFF_BFK);
  unsigned short* Bfv = (unsigned short*)(ws + OFF_BFV);
  const int idx0 = blockIdx.x * 256 + threadIdx.x;
  for (int idx = idx0; idx < 16*32*64; idx += 64*256) {
    int ks = idx >> 11, lt = (idx >> 6) & 31, l = idx & 63;
    int lcol = lt*16 + (l & 15), krow = ks*32 + ((l >> 4) << 3);
    unsigned short hk[8] __attribute__((aligned(16)));
    unsigned short hv[8] __attribute__((aligned(16)));
    for (int j = 0; j < 8; j++) {
      hk[j] = bfbits(Gm[(size_t)(krow + j)*HID + lcol]);
      hv[j] = bfbits(Nm[(size_t)lcol*HID + krow + j]);
    }
    *(uint4*)(Bfk + (size_t)idx*8) = *(uint4*)hk;
    *(uint4*)(Bfv + (size_t)idx*8) = *(uint4*)hv;
  }
}

// ---- k1: tagged h staging (wave wv covers u64 pair-cols [wv*32,+32), 16 batches) ----
#define STAGE_TAGGED(SLOT, TAGV)                                                      \
  {                                                                                   \
    const unsigned long long* _s = hb64 + ((size_t)(SLOT)*NBAT + b0)*(HID/2);         \
    const int _b = l >> 2, _pb = wv*32 + (l & 3)*8;                                   \
    unsigned long long _v[8];                                                         \
    _Pragma("unroll") for (int r = 0; r < 8; r++)                                     \
      _v[r] = ldg8(_s + (size_t)_b*(HID/2) + _pb + r);                                \
    _Pragma("unroll") for (int r = 0; r < 8; r++) {                                   \
      while ((int)(_v[r] & 3) != (TAGV)) {                                            \
        __builtin_amdgcn_s_sleep(1);                                                  \
        _v[r] = ldg8(_s + (size_t)_b*(HID/2) + _pb + r);                              \
      }                                                                               \
    }                                                                                 \
    _Pragma("unroll") for (int r = 0; r < 8; r++) {                                   \
      unsigned long long u = _v[r];                                                   \
      uint32_t hi2 = (uint32_t)((u >> 48) & 0xffffu) | ((uint32_t)((u >> 32) & 0xffffu) << 16); \
      uint32_t lo2 = ((uint32_t)((u >> 17) & 0x7fffu) << 1) | ((uint32_t)((u >> 2) & 0x7fffu) << 17); \
      *(uint32_t*)&s_hh[_b][(_pb + r)*2] = hi2;                                       \
      *(uint32_t*)&s_hl[_b][(_pb + r)*2] = lo2;                                       \
    }                                                                                 \
  }

// ---- k2 preloop: untagged full-tile unpack of k1's tagged pair format ----
#define STAGE_FULL_PAIR(SLOT)                                                         \
  {                                                                                   \
    const unsigned long long* _s = hb64 + ((size_t)(SLOT)*NBAT + b0)*(HID/2);         \
    const int _b = tid >> 5, _pb = (tid & 31)*8;                                      \
    _Pragma("unroll") for (int r = 0; r < 8; r++) {                                   \
      unsigned long long u = ldg8(_s + (size_t)_b*(HID/2) + _pb + r);                 \
      uint32_t hi2 = (uint32_t)((u >> 48) & 0xffffu) | ((uint32_t)((u >> 32) & 0xffffu) << 16); \
      uint32_t lo2 = ((uint32_t)((u >> 17) & 0x7fffu) << 1) | ((uint32_t)((u >> 2) & 0x7fffu) << 17); \
      *(uint32_t*)&s_hh[_b][(_pb + r)*2] = hi2;                                       \
      *(uint32_t*)&s_hl[_b][(_pb + r)*2] = lo2;                                       \
    }                                                                                 \
  }

// ---- k2 in-loop: per-wave slice stage, u32-per-unit {hi,lo} format (R7) ----
#define STAGE_SLICE8(srcPTR)                                                          \
  {                                                                                   \
    const unsigned long long* _s = (const unsigned long long*)(srcPTR);               \
    const int _half = l >> 5, _co = wv*32 + (l & 31);                                 \
    unsigned long long _tm[8];                                                        \
    _Pragma("unroll") for (int r = 0; r < 8; r++)                                     \
      _tm[r] = ldg8(_s + (size_t)(_half*8 + r)*(HID/2) + _co);                        \
    const int kk = _co*2;                                                             \
    _Pragma("unroll") for (int r = 0; r < 8; r++) {                                   \
      unsigned long long u = _tm[r];                                                  \
      int bb_ = _half*8 + r;                                                          \
      *(uint32_t*)&s_hh[bb_][kk] = (uint32_t)(u & 0xffffu) | (((uint32_t)(u >> 32) & 0xffffu) << 16); \
      *(uint32_t*)&s_hl[bb_][kk] = ((uint32_t)(u >> 16) & 0xffffu) | ((uint32_t)(u >> 48) << 16);     \
    }                                                                                 \
  }

#define WFRAG_INIT_512()                                                              \
  for (int slot = tid; slot < 2*16*64; slot += 512) {                                 \
    int T = slot >> 10, ks = (slot >> 6) & 15, l_ = slot & 63;                        \
    int rloc = T*16 + (l_ & 15);                                                      \
    int grow = (rloc >> 3)*HID + hs + (rloc & 7);                                     \
    int ko = ks*32 + ((l_ >> 4) << 3);                                                \
    const float* wp = &whh[(size_t)grow*HID + ko];                                    \
    unsigned short hi[8] __attribute__((aligned(16)));                                \
    unsigned short lo[8] __attribute__((aligned(16)));                                \
    for (int j = 0; j < 8; j++) {                                                     \
      uint32_t u = splitbf(wp[j]);                                                    \
      hi[j] = (unsigned short)u; lo[j] = (unsigned short)(u >> 16);                   \
    }                                                                                 \
    *(uint4*)&s_wf[T][ks][l_][0] = *(uint4*)hi;                                       \
    *(uint4*)&s_wl[T][ks][l_][0] = *(uint4*)lo;                                       \
  }

// k1 cell MFMA into parity-buffered s_pacc[PAR]
#define CELL_MFMA8(PAR)                                                               \
  {                                                                                   \
    f32x4 acc0 = {0.f,0.f,0.f,0.f}, acc1 = {0.f,0.f,0.f,0.f};                         \
    _Pragma("unroll") for (int kq = 0; kq < 2; kq++) {                                \
      const int ks = wv*2 + kq;                                                       \
      const int ko = ks*32 + (oc << 3);                                               \
      bf16x8 ahi = *(const bf16x8*)&s_hh[lm][ko];                                     \
      bf16x8 alo = *(const bf16x8*)&s_hl[lm][ko];                                     \
      bf16x8 b0h = *(const bf16x8*)&s_wf[0][ks][l][0];                                \
      bf16x8 b0l = *(const bf16x8*)&s_wl[0][ks][l][0];                                \
      bf16x8 b1h = *(const bf16x8*)&s_wf[1][ks][l][0];                                \
      bf16x8 b1l = *(const bf16x8*)&s_wl[1][ks][l][0];                                \
      acc0 = MFMA_B16(ahi, b0h, acc0, 0, 0, 0);                                       \
      acc0 = MFMA_B16(alo, b0h, acc0, 0, 0, 0);                                       \
      acc0 = MFMA_B16(ahi, b0l, acc0, 0, 0, 0);                                       \
      acc1 = MFMA_B16(ahi, b1h, acc1, 0, 0, 0);                                       \
      acc1 = MFMA_B16(alo, b1h, acc1, 0, 0, 0);                                       \
      acc1 = MFMA_B16(ahi, b1l, acc1, 0, 0, 0);                                       \
    }                                                                                 \
    _Pragma("unroll") for (int q = 0; q < 4; q++) {                                   \
      int idx = (oc*4 + q)*16 + lm;                                                   \
      s_pacc[PAR][wv][0][idx] = acc0[q];                                              \
      s_pacc[PAR][wv][1][idx] = acc1[q];                                              \
    }                                                                                 \
  }                                                                                   \
  __syncthreads();

// k2 cell MFMA, register weights, single s_pacc (safe: post-STAGE barrier pins waves)
#define CELL_MFMA8R()                                                                 \
  {                                                                                   \
    f32x4 acc0 = {0.f,0.f,0.f,0.f}, acc1 = {0.f,0.f,0.f,0.f};                         \
    _Pragma("unroll") for (int kq = 0; kq < 2; kq++) {                                \
      const int ks = wv*2 + kq;                                                       \
      const int ko = ks*32 + (oc << 3);                                               \
      bf16x8 ahi = *(const bf16x8*)&s_hh[lm][ko];                                     \
      bf16x8 alo = *(const bf16x8*)&s_hl[lm][ko];                                     \
      acc0 = MFMA_B16(ahi, wh0[kq], acc0, 0, 0, 0);                                   \
      acc0 = MFMA_B16(alo, wh0[kq], acc0, 0, 0, 0);                                   \
      acc0 = MFMA_B16(ahi, wl0[kq], acc0, 0, 0, 0);                                   \
      acc1 = MFMA_B16(ahi, wh1[kq], acc1, 0, 0, 0);                                   \
      acc1 = MFMA_B16(alo, wh1[kq], acc1, 0, 0, 0);                                   \
      acc1 = MFMA_B16(ahi, wl1[kq], acc1, 0, 0, 0);                                   \
    }                                                                                 \
    _Pragma("unroll") for (int q = 0; q < 4; q++) {                                   \
      int idx = (oc*4 + q)*16 + lm;                                                   \
      s_pacc[wv][0][idx] = acc0[q];                                                   \
      s_pacc[wv][1][idx] = acc1[q];                                                   \
    }                                                                                 \
  }                                                                                   \
  __syncthreads();

// k1: 64-thread gates, tagged u64 pair store
#define GATES2(PACC, SLOT, TAGV, EO_STORE)                                            \
  if (tid < 64) {                                                                     \
    const int b = tid >> 2, jp = tid & 3;                                             \
    const int j0 = jp*2, j1 = jp*2 + 1;                                               \
    float x = s_x[b];                                                                 \
    float zi0=0.f,zf0=0.f,zg0=0.f,zo0=0.f, zi1=0.f,zf1=0.f,zg1=0.f,zo1=0.f;           \
    _Pragma("unroll") for (int w = 0; w < 8; w++) {                                   \
      zi0 += PACC[w][0][b*16+j0];   zf0 += PACC[w][0][b*16+8+j0];                     \
      zg0 += PACC[w][1][b*16+j0];   zo0 += PACC[w][1][b*16+8+j0];                     \
      zi1 += PACC[w][0][b*16+j1];   zf1 += PACC[w][0][b*16+8+j1];                     \
      zg1 += PACC[w][1][b*16+j1];   zo1 += PACC[w][1][b*16+8+j1];                     \
    }                                                                                 \
    zi0 += x*s_wih[j0]    + s_bias[j0];    zi1 += x*s_wih[j1]    + s_bias[j1];        \
    zf0 += x*s_wih[8+j0]  + s_bias[8+j0];  zf1 += x*s_wih[8+j1]  + s_bias[8+j1];      \
    zg0 += x*s_wih[16+j0] + s_bias[16+j0]; zg1 += x*s_wih[16+j1] + s_bias[16+j1];     \
    zo0 += x*s_wih[24+j0] + s_bias[24+j0]; zo1 += x*s_wih[24+j1] + s_bias[24+j1];     \
    float c0 = s_c[b][j0];                                                            \
    c0 = sigm(zf0)*c0 + sigm(zi0)*tanhf(zg0);                                         \
    float h0v = sigm(zo0)*tanhf(c0); s_c[b][j0] = c0;                                 \
    float c1 = s_c[b][j1];                                                            \
    c1 = sigm(zf1)*c1 + sigm(zi1)*tanhf(zg1);                                         \
    float h1v = sigm(zo1)*tanhf(c1); s_c[b][j1] = c1;                                 \
    uint32_t sa = splitbf(h0v), sb2 = splitbf(h1v);                                   \
    unsigned long long pk = ((unsigned long long)(sa & 0xffffu) << 48)                \
                          | ((unsigned long long)(sb2 & 0xffffu) << 32)               \
                          | ((unsigned long long)((sa >> 17) & 0x7fffu) << 17)        \
                          | ((unsigned long long)((sb2 >> 17) & 0x7fffu) << 2)        \
                          | (unsigned long long)(TAGV);                               \
    stg64(&hb64[((size_t)(SLOT)*NBAT + b0 + b)*(HID/2) + jb*4 + jp], pk);             \
    EO_STORE                                                                          \
  }

// k2: 8-wave gates sum (R7)
#define GATES_SUM()                                                                   \
      float zi = 0.f, zf = 0.f, zg = 0.f, zo = 0.f;                                   \
      _Pragma("unroll") for (int w = 0; w < 8; w++) {                                 \
        zi += s_pacc[w][0][b*16+j];                                                   \
        zf += s_pacc[w][0][b*16+8+j];                                                 \
        zg += s_pacc[w][1][b*16+j];                                                   \
        zo += s_pacc[w][1][b*16+8+j];                                                 \
      }                                                                               \
      float x = s_x[b];                                                               \
      zi += x*s_wih[j]    + s_bias[j];                                                \
      zf += x*s_wih[8+j]  + s_bias[8+j];                                              \
      zg += x*s_wih[16+j] + s_bias[16+j];                                             \
      zo += x*s_wih[24+j] + s_bias[24+j];

__global__ __launch_bounds__(512) void k1_enc(
    const float* __restrict__ xin, const float* __restrict__ wih,
    const float* __restrict__ whh, const float* __restrict__ bih,
    const float* __restrict__ bhh, char* __restrict__ ws) {
  const int bk = blockIdx.x, tid = threadIdx.x;
  const int g = bk >> 6, jb = bk & 63;
  const int hs = jb * NH, b0 = g * GBAT;
  unsigned long long* hb64 = (unsigned long long*)(ws + OFF_HB);
  float* cbuf = (float*)(ws + OFF_CB);
  unsigned short* eo = (unsigned short*)(ws + OFF_EO);

  __shared__ __align__(16) unsigned short s_wf[2][16][64][8];
  __shared__ __align__(16) unsigned short s_wl[2][16][64][8];
  __shared__ __align__(16) unsigned short s_hh[GBAT][520];
  __shared__ __align__(16) unsigned short s_hl[GBAT][520];
  __shared__ float s_pacc[2][8][2][256];    // parity dbuf (GATES2 vs next CELL WAR)
  __shared__ float s_c[GBAT][NH];
  __shared__ float s_x[GBAT];
  __shared__ float s_wih[32], s_bias[32];

  WFRAG_INIT_512()
  if (tid < 32) {
    int grow = (tid >> 3)*HID + hs + (tid & 7);
    s_wih[tid] = wih[grow];
    s_bias[tid] = bih[grow] + bhh[grow];
  }
  for (int i = tid; i < GBAT*NH; i += 512) s_c[i >> 3][i & 7] = 0.f;
  __syncthreads();   // all init LDS visible before first CELL

  const int l = tid & 63, wv = tid >> 6;
  const int lm = l & 15, oc = l >> 4;

  for (int t = 0; t < SEQE; t++) {
    if (tid < GBAT) s_x[tid] = xin[(size_t)(b0 + tid)*SEQE + t];
    STAGE_TAGGED(t % 3, t & 3)
    CELL_MFMA8(t & 1)    // ends with syncthreads (s_pacc[t&1] ready)
    GATES2(s_pacc[t & 1], (t+1) % 3, (t+1) & 3,
      { *(uint32_t*)&eo[((size_t)(b0+b)*SEQE + t)*HID + hs + j0] =
            (sa & 0xffffu) | ((sb2 & 0xffffu) << 16); })
  }
  __syncthreads();   // R11 FIX: wave 0's final GATES2 s_c update must be visible
  if (tid < GBAT*NH)
    cbuf[(size_t)(b0 + (tid >> 3))*HID + hs + (tid & 7)] = s_c[tid >> 3][tid & 7];
}

// K~/V~ precompute (R5-verified, unchanged)
__global__ __launch_bounds__(256) void k0c_kv(char* __restrict__ ws) {
  const float* wqb = (const float*)(ws + OFF_WQB);
  const float* m0 = (const float*)(ws + OFF_M0);
  const float* scv = (const float*)(ws + OFF_SC);
  const unsigned short* Bfk = (const unsigned short*)(ws + OFF_BFK);
  const unsigned short* Bfv = (const unsigned short*)(ws + OFF_BFV);
  unsigned short* eoK = (unsigned short*)(ws + OFF_EO);
  unsigned short* Vt = (unsigned short*)(ws + OFF_VT);
  float* kbv = (float*)(ws + OFF_KB);
  const int b = blockIdx.x >> 4, s0 = (blockIdx.x & 15) * 32;
  const int tid = threadIdx.x;
  __shared__ __align__(16) unsigned short s_e[32][520];
  __shared__ float s_kb[32][8];
  {
    const uint4* src = (const uint4*)(eoK + ((size_t)b*SEQE + s0)*HID);
    #pragma unroll
    for (int r = 0; r < 8; r++) {
      int i = tid + r*256;
      uint4 v = src[i];
      int rr = i >> 6, cc = (i & 63)*8;
      *(uint4*)&s_e[rr][cc] = v;
    }
  }
  __syncthreads();
  const int l = tid & 63, wv = tid >> 6, lm = l & 15, oc = l >> 4;
  for (int nt = 0; nt < 8; nt++) {
    const int lt = wv*8 + nt;
    f32x4 accK0 = {0,0,0,0}, accK1 = {0,0,0,0}, accV0 = {0,0,0,0}, accV1 = {0,0,0,0};
    #pragma unroll
    for (int ks = 0; ks < 16; ks++) {
      bf16x8 yk = *(const bf16x8*)(Bfk + (((size_t)ks*32 + lt)*64 + l)*8);
      bf16x8 yv = *(const bf16x8*)(Bfv + (((size_t)ks*32 + lt)*64 + l)*8);
      bf16x8 xe0 = *(const bf16x8*)&s_e[lm][ks*32 + oc*8];
      bf16x8 xe1 = *(const bf16x8*)&s_e[16 + lm][ks*32 + oc*8];
      accK0 = MFMA_B16(xe0, yk, accK0, 0,0,0);
      accK1 = MFMA_B16(xe1, yk, accK1, 0,0,0);
      accV0 = MFMA_B16(xe0, yv, accV0, 0,0,0);
      accV1 = MFMA_B16(xe1, yv, accV1, 0,0,0);
    }
    const float wq = wqb[lt*16 + lm];
    #pragma unroll
    for (int st = 0; st < 2; st++) {
      const f32x4& aK = st ? accK1 : accK0;
      const f32x4& aV = st ? accV1 : accV0;
      #pragma unroll
      for (int q = 0; q < 4; q++)
        eoK[((size_t)b*SEQE + s0 + st*16 + oc*4 + q)*HID + lt*16 + lm] = bfbits(aK[q] + wq);
      unsigned short pv[4] __attribute__((aligned(8)));
      #pragma unroll
      for (int q = 0; q < 4; q++) pv[q] = bfbits(aV[q]);
      *(unsigned long long*)(Vt + ((size_t)b*HID + lt*16 + lm)*SEQE + s0 + st*16 + oc*4)
          = *(unsigned long long*)pv;
    }
  }
  {
    int s = tid >> 3, kc = tid & 7;
    float acc = 0.f;
    for (int i = 0; i < 64; i++) {
      int k = kc*64 + i;
      acc += bf2f((uint32_t)s_e[s][k]) * m0[k];
    }
    s_kb[s][kc] = acc;
  }
  __syncthreads();
  if (tid < 32) {
    float a = 0.f;
    for (int kc = 0; kc < 8; kc++) a += s_kb[tid][kc];
    kbv[(size_t)b*SEQE + s0 + tid] = a + scv[2];
  }
}

__global__ __launch_bounds__(512) void k2_dec(
    const float* __restrict__ xin, const float* __restrict__ wih,
    const float* __restrict__ whh, const float* __restrict__ bih,
    const float* __restrict__ bhh, const float* __restrict__ lng,
    const float* __restrict__ lnb, const float* __restrict__ outw,
    const float* __restrict__ outb, char* __restrict__ ws,
    float* __restrict__ dout) {
  const int bk = blockIdx.x, tid = threadIdx.x;
  const int g = bk >> 6, jb = bk & 63;
  const int hs = jb * NH, b0 = g * GBAT;
  uint32_t* hbuf = (uint32_t*)(ws + OFF_HB);
  unsigned long long* hb64 = (unsigned long long*)(ws + OFF_HB);
  float* cbuf = (float*)(ws + OFF_CB);
  float* ebp  = (float*)(ws + OFF_EBP);
  float* md   = (float*)(ws + OFF_MD);
  const float* n0v = (const float*)(ws + OFF_N0);
  const float* scv = (const float*)(ws + OFF_SC);
  const float* kbv = (const float*)(ws + OFF_KB);
  const unsigned short* Kt = (const unsigned short*)(ws + OFF_EO);
  const unsigned short* Vt = (const unsigned short*)(ws + OFF_VT);
  unsigned long long* xpk = (unsigned long long*)(ws + OFF_XPK);
  int* fl2 = (int*)(ws + OFF_FLG) + (NGRP + g) * GBLK * FLS;
  int* pfl = (int*)(ws + OFF_FLG) + (2*NGRP + g) * GBLK * FLS;

  __shared__ __align__(16) unsigned short s_hh[GBAT][520];
  __shared__ __align__(16) unsigned short s_hl[GBAT][520];
  __shared__ __align__(16) unsigned short s_kt[64][520];  // K~ rows 0-63 pinned
  __shared__ float s_pacc[8][2][256];
  __shared__ float s_c[GBAT][NH];
  __shared__ float s_x[GBAT];
  __shared__ float s_wih[32], s_bias[32];
  __shared__ float s_scores[128];
  __shared__ __align__(16) uint32_t s_pbf[64];
  __shared__ float s_red[32];
  __shared__ float s_ln[HID], s_n0f[HID];

  const int l = tid & 63, wv = tid >> 6;
  const int lm = l & 15, oc = l >> 4;
  const int bb = jb >> 2, scq = jb & 3, batch = b0 + bb;

  // cell weights -> registers (split-bf16 B-fragments)
  bf16x8 wh0[2], wl0[2], wh1[2], wl1[2];
  #pragma unroll
  for (int kq = 0; kq < 2; kq++) {
    const int ks = wv*2 + kq;
    #pragma unroll
    for (int T = 0; T < 2; T++) {
      int rloc = T*16 + lm;
      int grow = (rloc >> 3)*HID + hs + (rloc & 7);
      const float* wp = &whh[(size_t)grow*HID + ks*32 + oc*8];
      unsigned short hi8[8] __attribute__((aligned(16)));
      unsigned short lo8[8] __attribute__((aligned(16)));
      #pragma unroll
      for (int j = 0; j < 8; j++) {
        uint32_t u = splitbf(wp[j]);
        hi8[j] = (unsigned short)u; lo8[j] = (unsigned short)(u >> 16);
      }
      if (T == 0) { wh0[kq] = *(bf16x8*)hi8; wl0[kq] = *(bf16x8*)lo8; }
      else        { wh1[kq] = *(bf16x8*)hi8; wl1[kq] = *(bf16x8*)lo8; }
    }
  }
  // V~ slice -> registers (loop-invariant)
  bf16x8 vreg[4][4];
  {
    const unsigned short* vp = Vt + (size_t)batch*HID*SEQE + (size_t)scq*128;
    #pragma unroll
    for (int n = 0; n < 4; n++)
      #pragma unroll
      for (int ks = 0; ks < 4; ks++)
        vreg[n][ks] = *(const bf16x8*)(vp + (size_t)((wv*4 + n)*16 + lm)*SEQE + ks*32 + oc*8);
  }
  // K~ rows 0-63 -> LDS (loop-invariant)
  for (int i = tid; i < 4096; i += 512) {
    int row = i >> 6, cc = (i & 63) * 8;
    *(uint4*)&s_kt[row][cc] =
        *(const uint4*)(Kt + ((size_t)batch*SEQE + scq*128 + row)*HID + cc);
  }
  if (tid < 32) {
    int grow = (tid >> 3)*HID + hs + (tid & 7);
    s_wih[tid] = wih[grow];
    s_bias[tid] = bih[grow] + bhh[grow];
  }
  for (int i = tid; i < HID; i += 512) {
    s_ln[i] = outw[i] * lng[i];
    s_n0f[i] = n0v[i];
  }
  for (int i = tid; i < GBAT*NH; i += 512)
    s_c[i >> 3][i & 7] = cbuf[(size_t)(b0 + (i >> 3))*HID + hs + (i & 7)];
  const float Swg = scv[0], Swb = scv[1], ob0 = outb[0];

  // preloop: h_e in slot 2 (k1 tagged pair format; kernel boundary => no poll)
  STAGE_FULL_PAIR(2)
  if (tid < GBAT) s_x[tid] = xin[(size_t)(b0 + tid)*SEQD];
  __syncthreads();            // drains vmcnt: slot-2 reads complete
  if (tid == 0) stgi(&fl2[jb*FLS], 0);   // "finished reading h_e" (flags init -1)

  for (int t = 0; t < SEQD; t++) {
    // ---- cell ----
    CELL_MFMA8R()
    if (tid < GBLK) { POLL_GE(&fl2[tid*FLS], t - 1) }
    __syncthreads();
    if (tid < 128) {
      int b = tid >> 3, j = tid & 7;
      GATES_SUM()
      float c = s_c[b][j];
      c = sigm(zf)*c + sigm(zi)*tanhf(zg);
      float hv = sigm(zo)*tanhf(c);
      s_c[b][j] = c;
      stgu(&hbuf[(size_t)((t+1)%3)*NBAT*HID + (size_t)(b0+b)*HID + hs + j], splitbf(hv));
    }
    __syncthreads();          // drains vmcnt before flag
    if (tid == 0) stgi(&fl2[jb*FLS], t + 1);
    // ---- stage h_new (per-wave, 8-producer wait) ----
    if (l < 8) { POLL_GE(&fl2[(wv*8 + l)*FLS], t + 1) }
    CFENCE();
    STAGE_SLICE8(hbuf + (size_t)((t+1)%3)*NBAT*HID + (size_t)b0*HID)
    __syncthreads();          // full h_new row available
    // ---- scores: waves 0-3 LDS-pinned K~, waves 4-7 streamed (L2-resident) rows ----
    {
      f32x4 acc = {0.f,0.f,0.f,0.f};
      if (wv < 4) {
        #pragma unroll
        for (int ks = 0; ks < 16; ks++) {
          bf16x8 xh = *(const bf16x8*)&s_hh[bb][ks*32 + oc*8];
          bf16x8 yk = *(const bf16x8*)&s_kt[wv*16 + lm][ks*32 + oc*8];
          acc = MFMA_B16(xh, yk, acc, 0, 0, 0);
        }
      } else {
        const unsigned short* kp =
            Kt + ((size_t)batch*SEQE + scq*128 + 64 + (wv - 4)*16)*HID;
        #pragma unroll
        for (int ks = 0; ks < 16; ks++) {
          bf16x8 xh = *(const bf16x8*)&s_hh[bb][ks*32 + oc*8];
          bf16x8 yk = *(const bf16x8*)(kp + (size_t)lm*HID + ks*32 + oc*8);
          acc = MFMA_B16(xh, yk, acc, 0, 0, 0);
        }
      }
      if (oc == 0) s_scores[wv*16 + lm] = acc[0];
    }
    __syncthreads();
    float den_part = 0.f;
    if (tid < 128) {
      float sv = (s_scores[tid] + kbv[(size_t)batch*SEQE + scq*128 + tid]) * SCALE;
      den_part = __expf(sv);
      s_scores[tid] = den_part;
    }
    __syncthreads();
    if (tid < 64)
      s_pbf[tid] = (uint32_t)bfbits(s_scores[2*tid]) | ((uint32_t)bfbits(s_scores[2*tid+1]) << 16);
    if (tid < 128) {
      for (int off = 32; off; off >>= 1) den_part += __shfl_down(den_part, off);
      if ((tid & 63) == 0) s_red[tid >> 6] = den_part;
    }
    __syncthreads();
    if (tid == 0) stg(&md[batch*4 + scq], s_red[0] + s_red[1]);
    // ---- PV from registers ----
    {
      #pragma unroll
      for (int n = 0; n < 4; n++) {
        const int lv0 = (wv*4 + n)*16;
        f32x4 acc = {0.f,0.f,0.f,0.f};
        #pragma unroll
        for (int ks = 0; ks < 4; ks++) {
          bf16x8 xp = *(const bf16x8*)((const unsigned short*)s_pbf + ks*32 + oc*8);
          acc = MFMA_B16(xp, vreg[n][ks], acc, 0, 0, 0);
        }
        if (oc == 0) stg(&ebp[((size_t)batch*4 + scq)*HID + lv0 + lm], acc[0]);
      }
    }
    __syncthreads();          // drains vmcnt: ebp/md stores at coherence point
    if (tid == 0) stgi(&pfl[jb*FLS], t + 1);
    // ---- P3: combine + LN + out + x publish (blocks jb<16, batch b0+jb) ----
    if (jb < GBAT) {
      #pragma unroll
      for (int q = 0; q < 4; q++) { POLL_GE(&pfl[(4*jb + q)*FLS], t + 1) }
      CFENCE();
      const int mb = b0 + jb;
      if (tid < 4) s_red[tid] = ldg1(&md[mb*4 + tid]);
      __syncthreads();
      const float inv = 1.f / (s_red[0] + s_red[1] + s_red[2] + s_red[3]);
      if (tid < 256) {
        float sy = 0.f, sy2 = 0.f, sg = 0.f;
        #pragma unroll
        for (int u = 0; u < 2; u++) {
          const int lv = tid*2 + u;
          float p0 = ldg1(&ebp[((size_t)mb*4 + 0)*HID + lv]);
          float p1 = ldg1(&ebp[((size_t)mb*4 + 1)*HID + lv]);
          float p2 = ldg1(&ebp[((size_t)mb*4 + 2)*HID + lv]);
          float p3 = ldg1(&ebp[((size_t)mb*4 + 3)*HID + lv]);
          float hval = bf2f((uint32_t)s_hh[jb][lv]) + bf2f((uint32_t)s_hl[jb][lv]);
          float y = (p0 + p1 + p2 + p3)*inv + s_n0f[lv] + hval;
          sy += y; sy2 += y*y; sg += s_ln[lv]*y;
        }
        for (int off = 32; off; off >>= 1) {
          sy += __shfl_down(sy, off); sy2 += __shfl_down(sy2, off); sg += __shfl_down(sg, off);
        }
        if (l == 0) { s_red[8+wv] = sy; s_red[12+wv] = sy2; s_red[16+wv] = sg; }
      }
      __syncthreads();
      if (tid == 0) {
        float Sy  = s_red[8]  + s_red[9]  + s_red[10] + s_red[11];
        float Sy2 = s_red[12] + s_red[13] + s_red[14] + s_red[15];
        float Sg  = s_red[16] + s_red[17] + s_red[18] + s_red[19];
        float mu = Sy * (1.f/HID);
        float var = Sy2 * (1.f/HID) - mu*mu;
        float rs = rsqrtf(var + 1e-5f);
        float o = rs*(Sg - mu*Swg) + Swb + ob0;
        dout[(size_t)mb*SEQD + t] = o;
        union { float f; uint32_t u; } cv; cv.f = o;
        stg64(&xpk[mb], ((unsigned long long)cv.u << 32) | (uint32_t)(t + 1));
      }
    }
    // ---- x wait: packed {o, epoch} — data IS the flag ----
    if (tid < GBAT) {
      unsigned long long v;
      do { v = ldg8(&xpk[b0 + tid]); __builtin_amdgcn_s_sleep(1); }
      while ((uint32_t)v < (uint32_t)(t + 1));
      union { uint32_t u; float f; } cv; cv.u = (uint32_t)(v >> 32);
      s_x[tid] = cv.f;
    }
    CFENCE();
    // next iter: CELL's internal syncthreads orders s_x/s_pacc across waves
  }
}

extern "C" void kernel_launch(void* const* d_in, const int* in_sizes, int n_in,
                              void* d_out, int out_size, void* d_ws, size_t ws_size,
                              hipStream_t stream) {
  const float* enc_in = (const float*)d_in[0];
  const float* dec_in = (const float*)d_in[1];
  const float* ewih = (const float*)d_in[2];
  const float* ewhh = (const float*)d_in[3];
  const float* ebih = (const float*)d_in[4];
  const float* ebhh = (const float*)d_in[5];
  const float* dwih = (const float*)d_in[6];
  const float* dwhh = (const float*)d_in[7];
  const float* dbih = (const float*)d_in[8];
  const float* dbhh = (const float*)d_in[9];
  const float* aiw  = (const float*)d_in[10];
  const float* aib  = (const float*)d_in[11];
  const float* aow  = (const float*)d_in[12];
  const float* aob  = (const float*)d_in[13];
  const float* lng  = (const float*)d_in[14];
  const float* lnb  = (const float*)d_in[15];
  const float* outw = (const float*)d_in[16];
  const float* outb = (const float*)d_in[17];
  char* ws = (char*)d_ws;
  k0_prep<<<513, 256, 0, stream>>>(aiw, aib, aow, aob, outw, lng, lnb, ws);
  k0b_frag<<<64, 256, 0, stream>>>(ws);
  k1_enc<<<256, 512, 0, stream>>>(enc_in, ewih, ewhh, ebih, ebhh, ws);
  k0c_kv<<<1024, 256, 0, stream>>>(ws);
  k2_dec<<<256, 512, 0, stream>>>(dec_in, dwih, dwhh, dbih, dbhh,
                                  lng, lnb, outw, outb, ws, (float*)d_out);
}

// Round 12
// 2832.184 us; speedup vs baseline: 2.2866x; 2.2866x over previous
//
#include <hip/hip_runtime.h>
#include <hip/hip_bf16.h>
#include <stdint.h>

// Seq2Seq w/ attention, MI355X. R12 = R7 (PASS, 3024us) + provable deletions:
//  - lagged all-64 overwrite poll removed in k1 & k2: the 8 waves' stage polls
//    collectively check all 64 flags >= t (8x8=64) with a barrier before the
//    h-store; flag=t => finished stage(t-2) => slot overwritten at gates(t) is
//    no longer read (needs only >= t-1). One IF RT/step saved in both kernels.
//  - init barrier after WFRAG_INIT (latent race), tail barrier before cbuf.
// k1/k2 protocol otherwise byte-identical to R7 (flags fl/fl2/pfl/xpk, u32 h).

#define HID 512
#define NBAT 64
#define SEQE 512
#define SEQD 128
#define NGRP 4
#define GBAT 16
#define GBLK 64
#define NH 8
#define SCALE 0.04419417382415922f
#define FLS 16

typedef __attribute__((ext_vector_type(8))) short bf16x8;
typedef __attribute__((ext_vector_type(4))) float f32x4;
#define MFMA_B16 __builtin_amdgcn_mfma_f32_16x16x32_bf16

static constexpr size_t OFF_G   = 0;
static constexpr size_t OFF_NM  = OFF_G  + (size_t)HID*HID*4;
static constexpr size_t OFF_M0  = OFF_NM + (size_t)HID*HID*4;
static constexpr size_t OFF_N0  = OFF_M0 + 2048;
static constexpr size_t OFF_WQB = OFF_N0 + 2048;
static constexpr size_t OFF_SC  = OFF_WQB + 2048;                   // Swg, Swb, bqbk
static constexpr size_t OFF_HB  = OFF_SC + 256;                     // h 3-slot [3][B][H] u32(hi,lo)
static constexpr size_t OFF_CB  = OFF_HB + (size_t)3*NBAT*HID*4;    // c handoff f32
static constexpr size_t OFF_EBP = OFF_CB + (size_t)NBAT*HID*4;      // PV partials [B][4][H] f32
static constexpr size_t OFF_MD  = OFF_EBP + (size_t)NBAT*4*HID*4;   // den partials [B][4]
static constexpr size_t OFF_KB  = OFF_MD + (size_t)NBAT*4*4;        // kb [B][Se] f32
static constexpr size_t OFF_FLG = OFF_KB + (size_t)NBAT*SEQE*4;     // 3 sets x NGRP x 64 flags
static constexpr size_t OFF_XPK = OFF_FLG + (size_t)3*NGRP*GBLK*FLS*4; // [B] u64 {o,epoch}
static constexpr size_t OFF_BFK = ((OFF_XPK + 512 + 255) & ~(size_t)255);
static constexpr size_t OFF_BFV = OFF_BFK + (size_t)16*32*64*8*2;   // 512KB each
static constexpr size_t OFF_EO  = OFF_BFV + (size_t)16*32*64*8*2;   // eo then K~ [B][Se][H] bf16
static constexpr size_t OFF_VT  = OFF_EO + (size_t)NBAT*SEQE*HID*2; // V~t [B][H][Se] bf16

__device__ __forceinline__ float bf2f(uint32_t u) {
  union { float f; uint32_t i; } x; x.i = u << 16; return x.f;
}
__device__ __forceinline__ unsigned short bfbits(float f) {
  __hip_bfloat16 h = __float2bfloat16(f);
  return *(unsigned short*)&h;
}
__device__ __forceinline__ uint32_t splitbf(float f) {
  unsigned short hi = bfbits(f);
  union { uint32_t u; float ff; } c; c.u = (uint32_t)hi << 16;
  unsigned short lo = bfbits(f - c.ff);
  return (uint32_t)hi | ((uint32_t)lo << 16);
}
__device__ __forceinline__ float sigm(float x) { return 1.f / (1.f + __expf(-x)); }

__device__ __forceinline__ void stg(float* p, float v) {
  __hip_atomic_store(p, v, __ATOMIC_RELAXED, __HIP_MEMORY_SCOPE_AGENT);
}
__device__ __forceinline__ void stgu(uint32_t* p, uint32_t v) {
  __hip_atomic_store(p, v, __ATOMIC_RELAXED, __HIP_MEMORY_SCOPE_AGENT);
}
__device__ __forceinline__ void stgi(int* p, int v) {
  __hip_atomic_store(p, v, __ATOMIC_RELAXED, __HIP_MEMORY_SCOPE_AGENT);
}
__device__ __forceinline__ void stg64(unsigned long long* p, unsigned long long v) {
  __hip_atomic_store(p, v, __ATOMIC_RELAXED, __HIP_MEMORY_SCOPE_AGENT);
}
__device__ __forceinline__ float ldg1(const float* p) {
  return __hip_atomic_load((float*)p, __ATOMIC_RELAXED, __HIP_MEMORY_SCOPE_AGENT);
}
__device__ __forceinline__ int ldgi(const int* p) {
  return __hip_atomic_load((int*)p, __ATOMIC_RELAXED, __HIP_MEMORY_SCOPE_AGENT);
}
__device__ __forceinline__ unsigned long long ldg8(const void* p) {
  return __hip_atomic_load((unsigned long long*)p, __ATOMIC_RELAXED, __HIP_MEMORY_SCOPE_AGENT);
}

#define POLL_GE(addr, thr) \
  while (ldgi(addr) < (thr)) __builtin_amdgcn_s_sleep(1);
#define CFENCE() __asm__ __volatile__("" ::: "memory")

__global__ __launch_bounds__(256) void k0_prep(
    const float* __restrict__ aiw, const float* __restrict__ aib,
    const float* __restrict__ aow, const float* __restrict__ aob,
    const float* __restrict__ outw, const float* __restrict__ lng,
    const float* __restrict__ lnb, char* __restrict__ ws) {
  float* Gm = (float*)(ws + OFF_G);
  float* Nm = (float*)(ws + OFF_NM);
  float* m0 = (float*)(ws + OFF_M0);
  float* n0 = (float*)(ws + OFF_N0);
  float* wqb = (float*)(ws + OFF_WQB);
  float* sc = (float*)(ws + OFF_SC);
  const int blk = blockIdx.x, tid = threadIdx.x;
  if (blk == 512) {
    uint32_t* hb = (uint32_t*)(ws + OFF_HB);
    int* fl = (int*)(ws + OFF_FLG);
    unsigned long long* xpk = (unsigned long long*)(ws + OFF_XPK);
    for (int i = tid; i < 3*NBAT*HID; i += 256) hb[i] = 0u;          // all 3 slots zeroed
    for (int i = tid; i < 3*NGRP*GBLK*FLS; i += 256) fl[i] = 0;      // replay-safe
    for (int i = tid; i < NBAT; i += 256) xpk[i] = 0ull;
    for (int l = tid; l < HID; l += 256) {
      float s = 0.f;
      for (int i = 0; i < HID; i++) s += aib[i] * aiw[(size_t)(HID + i)*HID + l];
      m0[l] = s;  // Wk^T bq
    }
    for (int l = tid; l < HID; l += 256) {
      float s = 0.f;
      for (int i = 0; i < HID; i++) s += aiw[(size_t)i*HID + l] * aib[HID + i];
      wqb[l] = s;  // Wq^T bk
    }
    for (int j = tid; j < HID; j += 256) {
      float s = aob[j];
      for (int i = 0; i < HID; i++) s += aow[(size_t)j*HID + i] * aib[2*HID + i];
      n0[j] = s;  // aow*bv + aob
    }
    __shared__ float red[256];
    float a = 0.f, b = 0.f, d = 0.f;
    for (int l = tid; l < HID; l += 256) {
      a += outw[l]*lng[l]; b += outw[l]*lnb[l]; d += aib[l]*aib[HID + l];
    }
    red[tid] = a; __syncthreads();
    for (int st = 128; st; st >>= 1) { if (tid < st) red[tid] += red[tid + st]; __syncthreads(); }
    if (tid == 0) sc[0] = red[0];
    __syncthreads();
    red[tid] = b; __syncthreads();
    for (int st = 128; st; st >>= 1) { if (tid < st) red[tid] += red[tid + st]; __syncthreads(); }
    if (tid == 0) sc[1] = red[0];
    __syncthreads();
    red[tid] = d; __syncthreads();
    for (int st = 128; st; st >>= 1) { if (tid < st) red[tid] += red[tid + st]; __syncthreads(); }
    if (tid == 0) sc[2] = red[0];  // bq.bk
    return;
  }
  const bool isG = blk < 256;
  const int tb = isG ? blk : blk - 256;
  const int r0 = (tb >> 4) * 32, c0 = (tb & 15) * 32;
  __shared__ float sa[32][33], sb[32][33];
  float acc[4] = {0.f, 0.f, 0.f, 0.f};
  const int tr = tid >> 3, tc = (tid & 7) * 4;
  for (int i0 = 0; i0 < HID; i0 += 32) {
    __syncthreads();
    if (isG) {  // Gm[l][k] = sum_i Wk[i][l]*Wq[i][k]
      for (int j = 0; j < 4; j++) sa[tr][tc + j] = aiw[(size_t)(HID + i0 + tr)*HID + r0 + tc + j];
      for (int j = 0; j < 4; j++) sb[tr][tc + j] = aiw[(size_t)(i0 + tr)*HID + c0 + tc + j];
    } else {    // N[j][l] = sum_i aow[j][i]*Wv[i][l]
      for (int j = 0; j < 4; j++) sa[tr][tc + j] = aow[(size_t)(r0 + tr)*HID + i0 + tc + j];
      for (int j = 0; j < 4; j++) sb[tr][tc + j] = aiw[(size_t)(2*HID + i0 + tr)*HID + c0 + tc + j];
    }
    __syncthreads();
    if (isG) {
      for (int i = 0; i < 32; i++) {
        float a = sa[i][tr];
        for (int j = 0; j < 4; j++) acc[j] += a * sb[i][tc + j];
      }
    } else {
      for (int i = 0; i < 32; i++) {
        float a = sa[tr][i];
        for (int j = 0; j < 4; j++) acc[j] += a * sb[i][tc + j];
      }
    }
  }
  float* dst = isG ? Gm : Nm;
  for (int j = 0; j < 4; j++) dst[(size_t)(r0 + tr)*HID + c0 + tc + j] = acc[j];
}

// B-fragments (verified)
__global__ __launch_bounds__(256) void k0b_frag(char* __restrict__ ws) {
  const float* Gm = (const float*)(ws + OFF_G);
  const float* Nm = (const float*)(ws + OFF_NM);
  unsigned short* Bfk = (unsigned short*)(ws + OFF_BFK);
  unsigned short* Bfv = (unsigned short*)(ws + OFF_BFV);
  const int idx0 = blockIdx.x * 256 + threadIdx.x;
  for (int idx = idx0; idx < 16*32*64; idx += 64*256) {
    int ks = idx >> 11, lt = (idx >> 6) & 31, l = idx & 63;
    int lcol = lt*16 + (l & 15), krow = ks*32 + ((l >> 4) << 3);
    unsigned short hk[8] __attribute__((aligned(16)));
    unsigned short hv[8] __attribute__((aligned(16)));
    for (int j = 0; j < 8; j++) {
      hk[j] = bfbits(Gm[(size_t)(krow + j)*HID + lcol]);
      hv[j] = bfbits(Nm[(size_t)lcol*HID + krow + j]);
    }
    *(uint4*)(Bfk + (size_t)idx*8) = *(uint4*)hk;
    *(uint4*)(Bfv + (size_t)idx*8) = *(uint4*)hv;
  }
}

// full-tile stage, 512 threads (k2 preloop)
#define STAGE_FULL8(srcPTR)                                                           \
  {                                                                                   \
    const unsigned long long* _s = (const unsigned long long*)(srcPTR);               \
    unsigned long long _tm[8];                                                        \
    _Pragma("unroll") for (int r = 0; r < 8; r++) _tm[r] = ldg8(_s + tid + r*512);    \
    _Pragma("unroll") for (int r = 0; r < 8; r++) {                                   \
      int i = tid + r*512;                                                            \
      int bb_ = i >> 8, kk = (i & 255) * 2;                                           \
      unsigned long long u = _tm[r];                                                  \
      *(uint32_t*)&s_hh[bb_][kk] = (uint32_t)(u & 0xffffu) | (((uint32_t)(u >> 32) & 0xffffu) << 16); \
      *(uint32_t*)&s_hl[bb_][kk] = ((uint32_t)(u >> 16) & 0xffffu) | ((uint32_t)(u >> 48) << 16);     \
    }                                                                                 \
  }

// per-wave slice stage (8 waves): wave wv stages u64 cols [wv*32,+32) all 16 batches.
#define STAGE_SLICE8(srcPTR)                                                          \
  {                                                                                   \
    const unsigned long long* _s = (const unsigned long long*)(srcPTR);               \
    const int _half = l >> 5, _co = wv*32 + (l & 31);                                 \
    unsigned long long _tm[8];                                                        \
    _Pragma("unroll") for (int r = 0; r < 8; r++)                                     \
      _tm[r] = ldg8(_s + (size_t)(_half*8 + r)*(HID/2) + _co);                        \
    const int kk = _co*2;                                                             \
    _Pragma("unroll") for (int r = 0; r < 8; r++) {                                   \
      unsigned long long u = _tm[r];                                                  \
      int bb_ = _half*8 + r;                                                          \
      *(uint32_t*)&s_hh[bb_][kk] = (uint32_t)(u & 0xffffu) | (((uint32_t)(u >> 32) & 0xffffu) << 16); \
      *(uint32_t*)&s_hl[bb_][kk] = ((uint32_t)(u >> 16) & 0xffffu) | ((uint32_t)(u >> 48) << 16);     \
    }                                                                                 \
  }

#define WFRAG_INIT_512()                                                              \
  for (int slot = tid; slot < 2*16*64; slot += 512) {                                 \
    int T = slot >> 10, ks = (slot >> 6) & 15, l_ = slot & 63;                        \
    int rloc = T*16 + (l_ & 15);                                                      \
    int grow = (rloc >> 3)*HID + hs + (rloc & 7);                                     \
    int ko = ks*32 + ((l_ >> 4) << 3);                                                \
    const float* wp = &whh[(size_t)grow*HID + ko];                                    \
    unsigned short hi[8] __attribute__((aligned(16)));                                \
    unsigned short lo[8] __attribute__((aligned(16)));                                \
    for (int j = 0; j < 8; j++) {                                                     \
      uint32_t u = splitbf(wp[j]);                                                    \
      hi[j] = (unsigned short)u; lo[j] = (unsigned short)(u >> 16);                   \
    }                                                                                 \
    *(uint4*)&s_wf[T][ks][l_][0] = *(uint4*)hi;                                       \
    *(uint4*)&s_wl[T][ks][l_][0] = *(uint4*)lo;                                       \
  }

// 8-wave cell MFMA, LDS weights (k1): wave wv does ks = wv*2, wv*2+1
#define CELL_MFMA8()                                                                  \
  {                                                                                   \
    f32x4 acc0 = {0.f,0.f,0.f,0.f}, acc1 = {0.f,0.f,0.f,0.f};                         \
    _Pragma("unroll") for (int kq = 0; kq < 2; kq++) {                                \
      const int ks = wv*2 + kq;                                                       \
      const int ko = ks*32 + (oc << 3);                                               \
      bf16x8 ahi = *(const bf16x8*)&s_hh[lm][ko];                                     \
      bf16x8 alo = *(const bf16x8*)&s_hl[lm][ko];                                     \
      bf16x8 b0h = *(const bf16x8*)&s_wf[0][ks][l][0];                                \
      bf16x8 b0l = *(const bf16x8*)&s_wl[0][ks][l][0];                                \
      bf16x8 b1h = *(const bf16x8*)&s_wf[1][ks][l][0];                                \
      bf16x8 b1l = *(const bf16x8*)&s_wl[1][ks][l][0];                                \
      acc0 = MFMA_B16(ahi, b0h, acc0, 0, 0, 0);                                       \
      acc0 = MFMA_B16(alo, b0h, acc0, 0, 0, 0);                                       \
      acc0 = MFMA_B16(ahi, b0l, acc0, 0, 0, 0);                                       \
      acc1 = MFMA_B16(ahi, b1h, acc1, 0, 0, 0);                                       \
      acc1 = MFMA_B16(alo, b1h, acc1, 0, 0, 0);                                       \
      acc1 = MFMA_B16(ahi, b1l, acc1, 0, 0, 0);                                       \
    }                                                                                 \
    _Pragma("unroll") for (int q = 0; q < 4; q++) {                                   \
      int idx = (oc*4 + q)*16 + lm;                                                   \
      s_pacc[wv][0][idx] = acc0[q];                                                   \
      s_pacc[wv][1][idx] = acc1[q];                                                   \
    }                                                                                 \
  }                                                                                   \
  __syncthreads();

// 8-wave cell MFMA, register weights (k2)
#define CELL_MFMA8R()                                                                 \
  {                                                                                   \
    f32x4 acc0 = {0.f,0.f,0.f,0.f}, acc1 = {0.f,0.f,0.f,0.f};                         \
    _Pragma("unroll") for (int kq = 0; kq < 2; kq++) {                                \
      const int ks = wv*2 + kq;                                                       \
      const int ko = ks*32 + (oc << 3);                                               \
      bf16x8 ahi = *(const bf16x8*)&s_hh[lm][ko];                                     \
      bf16x8 alo = *(const bf16x8*)&s_hl[lm][ko];                                     \
      acc0 = MFMA_B16(ahi, wh0[kq], acc0, 0, 0, 0);                                   \
      acc0 = MFMA_B16(alo, wh0[kq], acc0, 0, 0, 0);                                   \
      acc0 = MFMA_B16(ahi, wl0[kq], acc0, 0, 0, 0);                                   \
      acc1 = MFMA_B16(ahi, wh1[kq], acc1, 0, 0, 0);                                   \
      acc1 = MFMA_B16(alo, wh1[kq], acc1, 0, 0, 0);                                   \
      acc1 = MFMA_B16(ahi, wl1[kq], acc1, 0, 0, 0);                                   \
    }                                                                                 \
    _Pragma("unroll") for (int q = 0; q < 4; q++) {                                   \
      int idx = (oc*4 + q)*16 + lm;                                                   \
      s_pacc[wv][0][idx] = acc0[q];                                                   \
      s_pacc[wv][1][idx] = acc1[q];                                                   \
    }                                                                                 \
  }                                                                                   \
  __syncthreads();

#define GATES_SUM()                                                                   \
      float zi = 0.f, zf = 0.f, zg = 0.f, zo = 0.f;                                   \
      _Pragma("unroll") for (int w = 0; w < 8; w++) {                                 \
        zi += s_pacc[w][0][b*16+j];                                                   \
        zf += s_pacc[w][0][b*16+8+j];                                                 \
        zg += s_pacc[w][1][b*16+j];                                                   \
        zo += s_pacc[w][1][b*16+8+j];                                                 \
      }                                                                               \
      float x = s_x[b];                                                               \
      zi += x*s_wih[j]    + s_bias[j];                                                \
      zf += x*s_wih[8+j]  + s_bias[8+j];                                              \
      zg += x*s_wih[16+j] + s_bias[16+j];                                             \
      zo += x*s_wih[24+j] + s_bias[24+j];

__global__ __launch_bounds__(512) void k1_enc(
    const float* __restrict__ xin, const float* __restrict__ wih,
    const float* __restrict__ whh, const float* __restrict__ bih,
    const float* __restrict__ bhh, char* __restrict__ ws) {
  const int bk = blockIdx.x, tid = threadIdx.x;
  const int g = bk >> 6, jb = bk & 63;
  const int hs = jb * NH, b0 = g * GBAT;
  uint32_t* hbuf = (uint32_t*)(ws + OFF_HB);
  float* cbuf = (float*)(ws + OFF_CB);
  unsigned short* eo = (unsigned short*)(ws + OFF_EO);
  int* fl = (int*)(ws + OFF_FLG) + g * GBLK * FLS;

  __shared__ __align__(16) unsigned short s_wf[2][16][64][8];
  __shared__ __align__(16) unsigned short s_wl[2][16][64][8];
  __shared__ __align__(16) unsigned short s_hh[GBAT][520];
  __shared__ __align__(16) unsigned short s_hl[GBAT][520];
  __shared__ float s_pacc[8][2][256];
  __shared__ float s_c[GBAT][NH];
  __shared__ float s_x[GBAT];
  __shared__ float s_wih[32], s_bias[32];

  WFRAG_INIT_512()
  if (tid < 32) {
    int grow = (tid >> 3)*HID + hs + (tid & 7);
    s_wih[tid] = wih[grow];
    s_bias[tid] = bih[grow] + bhh[grow];
  }
  for (int i = tid; i < GBAT*NH; i += 512) s_c[i >> 3][i & 7] = 0.f;
  __syncthreads();   // init LDS (weights, biases, c) visible before first CELL

  const int l = tid & 63, wv = tid >> 6;
  const int lm = l & 15, oc = l >> 4;

  for (int t = 0; t < SEQE; t++) {
    if (tid < GBAT) s_x[tid] = xin[(size_t)(b0 + tid)*SEQE + t];
    // wave-local wait: my 8 h-producers stored h_t. Collectively (8 waves x 8)
    // ALL 64 flags checked >= t, barrier-ordered before the h(t+1) store below
    // => lagged overwrite poll is redundant (deleted vs R7).
    if (l < 8) { POLL_GE(&fl[(wv*8 + l)*FLS], t) }
    CFENCE();
    STAGE_SLICE8(hbuf + (size_t)(t % 3)*NBAT*HID + (size_t)b0*HID)
    CELL_MFMA8()   // trailing syncthreads: s_pacc ready AND all polls passed
    if (tid < 128) {
      int b = tid >> 3, j = tid & 7;
      GATES_SUM()
      float c = s_c[b][j];
      c = sigm(zf)*c + sigm(zi)*tanhf(zg);
      float hv = sigm(zo)*tanhf(c);
      s_c[b][j] = c;
      uint32_t pk = splitbf(hv);
      stgu(&hbuf[(size_t)((t+1)%3)*NBAT*HID + (size_t)(b0+b)*HID + hs + j], pk);
      eo[((size_t)(b0+b)*SEQE + t)*HID + hs + j] = (unsigned short)(pk & 0xffffu);
    }
    __syncthreads();  // drains vmcnt: h stores at coherence point before flag
    if (tid == 0) stgi(&fl[jb*FLS], t + 1);
  }
  __syncthreads();   // final s_c updates visible to all
  if (tid < GBAT*NH)
    cbuf[(size_t)(b0 + (tid >> 3))*HID + hs + (tid & 7)] = s_c[tid >> 3][tid & 7];
}

// K~/V~ precompute (R5-verified, unchanged)
__global__ __launch_bounds__(256) void k0c_kv(char* __restrict__ ws) {
  const float* wqb = (const float*)(ws + OFF_WQB);
  const float* m0 = (const float*)(ws + OFF_M0);
  const float* scv = (const float*)(ws + OFF_SC);
  const unsigned short* Bfk = (const unsigned short*)(ws + OFF_BFK);
  const unsigned short* Bfv = (const unsigned short*)(ws + OFF_BFV);
  unsigned short* eoK = (unsigned short*)(ws + OFF_EO);
  unsigned short* Vt = (unsigned short*)(ws + OFF_VT);
  float* kbv = (float*)(ws + OFF_KB);
  const int b = blockIdx.x >> 4, s0 = (blockIdx.x & 15) * 32;
  const int tid = threadIdx.x;
  __shared__ __align__(16) unsigned short s_e[32][520];
  __shared__ float s_kb[32][8];
  {
    const uint4* src = (const uint4*)(eoK + ((size_t)b*SEQE + s0)*HID);
    #pragma unroll
    for (int r = 0; r < 8; r++) {
      int i = tid + r*256;
      uint4 v = src[i];
      int rr = i >> 6, cc = (i & 63)*8;
      *(uint4*)&s_e[rr][cc] = v;
    }
  }
  __syncthreads();
  const int l = tid & 63, wv = tid >> 6, lm = l & 15, oc = l >> 4;
  for (int nt = 0; nt < 8; nt++) {
    const int lt = wv*8 + nt;
    f32x4 accK0 = {0,0,0,0}, accK1 = {0,0,0,0}, accV0 = {0,0,0,0}, accV1 = {0,0,0,0};
    #pragma unroll
    for (int ks = 0; ks < 16; ks++) {
      bf16x8 yk = *(const bf16x8*)(Bfk + (((size_t)ks*32 + lt)*64 + l)*8);
      bf16x8 yv = *(const bf16x8*)(Bfv + (((size_t)ks*32 + lt)*64 + l)*8);
      bf16x8 xe0 = *(const bf16x8*)&s_e[lm][ks*32 + oc*8];
      bf16x8 xe1 = *(const bf16x8*)&s_e[16 + lm][ks*32 + oc*8];
      accK0 = MFMA_B16(xe0, yk, accK0, 0,0,0);
      accK1 = MFMA_B16(xe1, yk, accK1, 0,0,0);
      accV0 = MFMA_B16(xe0, yv, accV0, 0,0,0);
      accV1 = MFMA_B16(xe1, yv, accV1, 0,0,0);
    }
    const float wq = wqb[lt*16 + lm];
    #pragma unroll
    for (int st = 0; st < 2; st++) {
      const f32x4& aK = st ? accK1 : accK0;
      const f32x4& aV = st ? accV1 : accV0;
      #pragma unroll
      for (int q = 0; q < 4; q++)
        eoK[((size_t)b*SEQE + s0 + st*16 + oc*4 + q)*HID + lt*16 + lm] = bfbits(aK[q] + wq);
      unsigned short pv[4] __attribute__((aligned(8)));
      #pragma unroll
      for (int q = 0; q < 4; q++) pv[q] = bfbits(aV[q]);
      *(unsigned long long*)(Vt + ((size_t)b*HID + lt*16 + lm)*SEQE + s0 + st*16 + oc*4)
          = *(unsigned long long*)pv;
    }
  }
  {
    int s = tid >> 3, kc = tid & 7;
    float acc = 0.f;
    for (int i = 0; i < 64; i++) {
      int k = kc*64 + i;
      acc += bf2f((uint32_t)s_e[s][k]) * m0[k];
    }
    s_kb[s][kc] = acc;
  }
  __syncthreads();
  if (tid < 32) {
    float a = 0.f;
    for (int kc = 0; kc < 8; kc++) a += s_kb[tid][kc];
    kbv[(size_t)b*SEQE + s0 + tid] = a + scv[2];
  }
}

__global__ __launch_bounds__(512) void k2_dec(
    const float* __restrict__ xin, const float* __restrict__ wih,
    const float* __restrict__ whh, const float* __restrict__ bih,
    const float* __restrict__ bhh, const float* __restrict__ lng,
    const float* __restrict__ lnb, const float* __restrict__ outw,
    const float* __restrict__ outb, char* __restrict__ ws,
    float* __restrict__ dout) {
  const int bk = blockIdx.x, tid = threadIdx.x;
  const int g = bk >> 6, jb = bk & 63;
  const int hs = jb * NH, b0 = g * GBAT;
  uint32_t* hbuf = (uint32_t*)(ws + OFF_HB);
  float* cbuf = (float*)(ws + OFF_CB);
  float* ebp  = (float*)(ws + OFF_EBP);
  float* md   = (float*)(ws + OFF_MD);
  const float* n0v = (const float*)(ws + OFF_N0);
  const float* scv = (const float*)(ws + OFF_SC);
  const float* kbv = (const float*)(ws + OFF_KB);
  const unsigned short* Kt = (const unsigned short*)(ws + OFF_EO);
  const unsigned short* Vt = (const unsigned short*)(ws + OFF_VT);
  unsigned long long* xpk = (unsigned long long*)(ws + OFF_XPK);
  int* fl2 = (int*)(ws + OFF_FLG) + (NGRP + g) * GBLK * FLS;
  int* pfl = (int*)(ws + OFF_FLG) + (2*NGRP + g) * GBLK * FLS;

  __shared__ __align__(16) unsigned short s_hh[GBAT][520];
  __shared__ __align__(16) unsigned short s_hl[GBAT][520];
  __shared__ __align__(16) unsigned short s_kt[64][520];  // K~ rows 0-63 pinned
  __shared__ float s_pacc[8][2][256];
  __shared__ float s_c[GBAT][NH];
  __shared__ float s_x[GBAT];
  __shared__ float s_wih[32], s_bias[32];
  __shared__ float s_scores[128];
  __shared__ __align__(16) uint32_t s_pbf[64];
  __shared__ float s_red[32];
  __shared__ float s_ln[HID], s_n0f[HID];

  const int l = tid & 63, wv = tid >> 6;
  const int lm = l & 15, oc = l >> 4;
  const int bb = jb >> 2, scq = jb & 3, batch = b0 + bb;

  // cell weights -> registers (split-bf16 B-fragments)
  bf16x8 wh0[2], wl0[2], wh1[2], wl1[2];
  #pragma unroll
  for (int kq = 0; kq < 2; kq++) {
    const int ks = wv*2 + kq;
    #pragma unroll
    for (int T = 0; T < 2; T++) {
      int rloc = T*16 + lm;
      int grow = (rloc >> 3)*HID + hs + (rloc & 7);
      const float* wp = &whh[(size_t)grow*HID + ks*32 + oc*8];
      unsigned short hi8[8] __attribute__((aligned(16)));
      unsigned short lo8[8] __attribute__((aligned(16)));
      #pragma unroll
      for (int j = 0; j < 8; j++) {
        uint32_t u = splitbf(wp[j]);
        hi8[j] = (unsigned short)u; lo8[j] = (unsigned short)(u >> 16);
      }
      if (T == 0) { wh0[kq] = *(bf16x8*)hi8; wl0[kq] = *(bf16x8*)lo8; }
      else        { wh1[kq] = *(bf16x8*)hi8; wl1[kq] = *(bf16x8*)lo8; }
    }
  }
  // V~ slice -> registers (loop-invariant)
  bf16x8 vreg[4][4];
  {
    const unsigned short* vp = Vt + (size_t)batch*HID*SEQE + (size_t)scq*128;
    #pragma unroll
    for (int n = 0; n < 4; n++)
      #pragma unroll
      for (int ks = 0; ks < 4; ks++)
        vreg[n][ks] = *(const bf16x8*)(vp + (size_t)((wv*4 + n)*16 + lm)*SEQE + ks*32 + oc*8);
  }
  // K~ rows 0-63 -> LDS (loop-invariant)
  for (int i = tid; i < 4096; i += 512) {
    int row = i >> 6, cc = (i & 63) * 8;
    *(uint4*)&s_kt[row][cc] =
        *(const uint4*)(Kt + ((size_t)batch*SEQE + scq*128 + row)*HID + cc);
  }
  if (tid < 32) {
    int grow = (tid >> 3)*HID + hs + (tid & 7);
    s_wih[tid] = wih[grow];
    s_bias[tid] = bih[grow] + bhh[grow];
  }
  for (int i = tid; i < HID; i += 512) {
    s_ln[i] = outw[i] * lng[i];
    s_n0f[i] = n0v[i];
  }
  for (int i = tid; i < GBAT*NH; i += 512)
    s_c[i >> 3][i & 7] = cbuf[(size_t)(b0 + (i >> 3))*HID + hs + (i & 7)];
  const float Swg = scv[0], Swb = scv[1], ob0 = outb[0];

  // preloop: h_e lives in slot SEQE%3 == 2 (k1's final store, u32 format)
  STAGE_FULL8(hbuf + (size_t)2*NBAT*HID + (size_t)b0*HID)
  if (tid < GBAT) s_x[tid] = xin[(size_t)(b0 + tid)*SEQD];
  __syncthreads();

  for (int t = 0; t < SEQD; t++) {
    // ---- cell: h(t+1) from s_hh (h(t)). Overwrite safety of slot (t+1)%3:
    // prev iter's stage polled fl2 >= t collectively (all 64), barrier-ordered
    // before this store => all blocks past stage(t-2) => lagged poll deleted.
    CELL_MFMA8R()   // trailing syncthreads
    if (tid < 128) {
      int b = tid >> 3, j = tid & 7;
      GATES_SUM()
      float c = s_c[b][j];
      c = sigm(zf)*c + sigm(zi)*tanhf(zg);
      float hv = sigm(zo)*tanhf(c);
      s_c[b][j] = c;
      stgu(&hbuf[(size_t)((t+1)%3)*NBAT*HID + (size_t)(b0+b)*HID + hs + j], splitbf(hv));
    }
    __syncthreads();          // drains vmcnt before flag
    if (tid == 0) stgi(&fl2[jb*FLS], t + 1);
    // ---- stage h(t+1) (per-wave, 8-producer wait; 8x8 = all 64 checked) ----
    if (l < 8) { POLL_GE(&fl2[(wv*8 + l)*FLS], t + 1) }
    CFENCE();
    STAGE_SLICE8(hbuf + (size_t)((t+1)%3)*NBAT*HID + (size_t)b0*HID)
    __syncthreads();          // full h(t+1) row available
    // ---- scores: waves 0-3 LDS-pinned K~, waves 4-7 streamed (L2-resident) ----
    {
      f32x4 acc = {0.f,0.f,0.f,0.f};
      if (wv < 4) {
        #pragma unroll
        for (int ks = 0; ks < 16; ks++) {
          bf16x8 xh = *(const bf16x8*)&s_hh[bb][ks*32 + oc*8];
          bf16x8 yk = *(const bf16x8*)&s_kt[wv*16 + lm][ks*32 + oc*8];
          acc = MFMA_B16(xh, yk, acc, 0, 0, 0);
        }
      } else {
        const unsigned short* kp =
            Kt + ((size_t)batch*SEQE + scq*128 + 64 + (wv - 4)*16)*HID;
        #pragma unroll
        for (int ks = 0; ks < 16; ks++) {
          bf16x8 xh = *(const bf16x8*)&s_hh[bb][ks*32 + oc*8];
          bf16x8 yk = *(const bf16x8*)(kp + (size_t)lm*HID + ks*32 + oc*8);
          acc = MFMA_B16(xh, yk, acc, 0, 0, 0);
        }
      }
      if (oc == 0) s_scores[wv*16 + lm] = acc[0];
    }
    __syncthreads();
    float den_part = 0.f;
    if (tid < 128) {
      float sv = (s_scores[tid] + kbv[(size_t)batch*SEQE + scq*128 + tid]) * SCALE;
      den_part = __expf(sv);
      s_scores[tid] = den_part;
    }
    __syncthreads();
    if (tid < 64)
      s_pbf[tid] = (uint32_t)bfbits(s_scores[2*tid]) | ((uint32_t)bfbits(s_scores[2*tid+1]) << 16);
    if (tid < 128) {
      for (int off = 32; off; off >>= 1) den_part += __shfl_down(den_part, off);
      if ((tid & 63) == 0) s_red[tid >> 6] = den_part;
    }
    __syncthreads();
    if (tid == 0) stg(&md[batch*4 + scq], s_red[0] + s_red[1]);
    // ---- PV from registers ----
    {
      #pragma unroll
      for (int n = 0; n < 4; n++) {
        const int lv0 = (wv*4 + n)*16;
        f32x4 acc = {0.f,0.f,0.f,0.f};
        #pragma unroll
        for (int ks = 0; ks < 4; ks++) {
          bf16x8 xp = *(const bf16x8*)((const unsigned short*)s_pbf + ks*32 + oc*8);
          acc = MFMA_B16(xp, vreg[n][ks], acc, 0, 0, 0);
        }
        if (oc == 0) stg(&ebp[((size_t)batch*4 + scq)*HID + lv0 + lm], acc[0]);
      }
    }
    __syncthreads();          // drains vmcnt: ebp/md stores at coherence point
    if (tid == 0) stgi(&pfl[jb*FLS], t + 1);
    // ---- P3: combine + LN + out + x publish (blocks jb<16, batch b0+jb) ----
    if (jb < GBAT) {
      #pragma unroll
      for (int q = 0; q < 4; q++) { POLL_GE(&pfl[(4*jb + q)*FLS], t + 1) }
      CFENCE();
      const int mb = b0 + jb;
      if (tid < 4) s_red[tid] = ldg1(&md[mb*4 + tid]);
      __syncthreads();
      const float inv = 1.f / (s_red[0] + s_red[1] + s_red[2] + s_red[3]);
      if (tid < 256) {
        float sy = 0.f, sy2 = 0.f, sg = 0.f;
        #pragma unroll
        for (int u = 0; u < 2; u++) {
          const int lv = tid*2 + u;
          float p0 = ldg1(&ebp[((size_t)mb*4 + 0)*HID + lv]);
          float p1 = ldg1(&ebp[((size_t)mb*4 + 1)*HID + lv]);
          float p2 = ldg1(&ebp[((size_t)mb*4 + 2)*HID + lv]);
          float p3 = ldg1(&ebp[((size_t)mb*4 + 3)*HID + lv]);
          float hval = bf2f((uint32_t)s_hh[jb][lv]) + bf2f((uint32_t)s_hl[jb][lv]);
          float y = (p0 + p1 + p2 + p3)*inv + s_n0f[lv] + hval;
          sy += y; sy2 += y*y; sg += s_ln[lv]*y;
        }
        for (int off = 32; off; off >>= 1) {
          sy += __shfl_down(sy, off); sy2 += __shfl_down(sy2, off); sg += __shfl_down(sg, off);
        }
        if (l == 0) { s_red[8+wv] = sy; s_red[12+wv] = sy2; s_red[16+wv] = sg; }
      }
      __syncthreads();
      if (tid == 0) {
        float Sy  = s_red[8]  + s_red[9]  + s_red[10] + s_red[11];
        float Sy2 = s_red[12] + s_red[13] + s_red[14] + s_red[15];
        float Sg  = s_red[16] + s_red[17] + s_red[18] + s_red[19];
        float mu = Sy * (1.f/HID);
        float var = Sy2 * (1.f/HID) - mu*mu;
        float rs = rsqrtf(var + 1e-5f);
        float o = rs*(Sg - mu*Swg) + Swb + ob0;
        dout[(size_t)mb*SEQD + t] = o;
        union { float f; uint32_t u; } cv; cv.f = o;
        stg64(&xpk[mb], ((unsigned long long)cv.u << 32) | (uint32_t)(t + 1));
      }
    }
    // ---- x wait: packed {o, epoch} — data IS the flag ----
    if (tid < GBAT) {
      unsigned long long v;
      do { v = ldg8(&xpk[b0 + tid]); __builtin_amdgcn_s_sleep(1); }
      while ((uint32_t)v < (uint32_t)(t + 1));
      union { uint32_t u; float f; } cv; cv.u = (uint32_t)(v >> 32);
      s_x[tid] = cv.f;
    }
    CFENCE();
    // next iter: CELL's internal syncthreads orders s_x/s_pacc across waves
  }
}

extern "C" void kernel_launch(void* const* d_in, const int* in_sizes, int n_in,
                              void* d_out, int out_size, void* d_ws, size_t ws_size,
                              hipStream_t stream) {
  const float* enc_in = (const float*)d_in[0];
  const float* dec_in = (const float*)d_in[1];
  const float* ewih = (const float*)d_in[2];
  const float* ewhh = (const float*)d_in[3];
  const float* ebih = (const float*)d_in[4];
  const float* ebhh = (const float*)d_in[5];
  const float* dwih = (const float*)d_in[6];
  const float* dwhh = (const float*)d_in[7];
  const float* dbih = (const float*)d_in[8];
  const float* dbhh = (const float*)d_in[9];
  const float* aiw  = (const float*)d_in[10];
  const float* aib  = (const float*)d_in[11];
  const float* aow  = (const float*)d_in[12];
  const float* aob  = (const float*)d_in[13];
  const float* lng  = (const float*)d_in[14];
  const float* lnb  = (const float*)d_in[15];
  const float* outw = (const float*)d_in[16];
  const float* outb = (const float*)d_in[17];
  char* ws = (char*)d_ws;
  k0_prep<<<513, 256, 0, stream>>>(aiw, aib, aow, aob, outw, lng, lnb, ws);
  k0b_frag<<<64, 256, 0, stream>>>(ws);
  k1_enc<<<256, 512, 0, stream>>>(enc_in, ewih, ewhh, ebih, ebhh, ws);
  k0c_kv<<<1024, 256, 0, stream>>>(ws);
  k2_dec<<<256, 512, 0, stream>>>(dec_in, dwih, dwhh, dbih, dbhh,
                                  lng, lnb, outw, outb, ws, (float*)d_out);
}

// Round 13
// 2658.693 us; speedup vs baseline: 2.4358x; 1.0653x over previous
//
#include <hip/hip_runtime.h>
#include <hip/hip_bf16.h>
#include <stdint.h>

// Seq2Seq w/ attention, MI355X. R13 = R12 (PASS, 2832us) + k2 latency overlap:
//  - x-wait moved from loop tail to after CELL (next cell overlaps P3->xpk chain).
//    Safety: xpk overwrite to epoch t+1 requires all-64 fl2>=t+1 (collective stage
//    polls) which requires every block's x-wait(t) read -> GE poll never sees a
//    future epoch.
//  - P3 remapped to scq==0 blocks (own batch): chunk-0 partials + own denominator
//    from LDS (s_own/s_d0); only 3 remote pfl polls + 3 remote ebp chunks.
// k1 unchanged (at 2-RT latency floor).

#define HID 512
#define NBAT 64
#define SEQE 512
#define SEQD 128
#define NGRP 4
#define GBAT 16
#define GBLK 64
#define NH 8
#define SCALE 0.04419417382415922f
#define FLS 16

typedef __attribute__((ext_vector_type(8))) short bf16x8;
typedef __attribute__((ext_vector_type(4))) float f32x4;
#define MFMA_B16 __builtin_amdgcn_mfma_f32_16x16x32_bf16

static constexpr size_t OFF_G   = 0;
static constexpr size_t OFF_NM  = OFF_G  + (size_t)HID*HID*4;
static constexpr size_t OFF_M0  = OFF_NM + (size_t)HID*HID*4;
static constexpr size_t OFF_N0  = OFF_M0 + 2048;
static constexpr size_t OFF_WQB = OFF_N0 + 2048;
static constexpr size_t OFF_SC  = OFF_WQB + 2048;                   // Swg, Swb, bqbk
static constexpr size_t OFF_HB  = OFF_SC + 256;                     // h 3-slot [3][B][H] u32(hi,lo)
static constexpr size_t OFF_CB  = OFF_HB + (size_t)3*NBAT*HID*4;    // c handoff f32
static constexpr size_t OFF_EBP = OFF_CB + (size_t)NBAT*HID*4;      // PV partials [B][4][H] f32
static constexpr size_t OFF_MD  = OFF_EBP + (size_t)NBAT*4*HID*4;   // den partials [B][4]
static constexpr size_t OFF_KB  = OFF_MD + (size_t)NBAT*4*4;        // kb [B][Se] f32
static constexpr size_t OFF_FLG = OFF_KB + (size_t)NBAT*SEQE*4;     // 3 sets x NGRP x 64 flags
static constexpr size_t OFF_XPK = OFF_FLG + (size_t)3*NGRP*GBLK*FLS*4; // [B] u64 {o,epoch}
static constexpr size_t OFF_BFK = ((OFF_XPK + 512 + 255) & ~(size_t)255);
static constexpr size_t OFF_BFV = OFF_BFK + (size_t)16*32*64*8*2;   // 512KB each
static constexpr size_t OFF_EO  = OFF_BFV + (size_t)16*32*64*8*2;   // eo then K~ [B][Se][H] bf16
static constexpr size_t OFF_VT  = OFF_EO + (size_t)NBAT*SEQE*HID*2; // V~t [B][H][Se] bf16

__device__ __forceinline__ float bf2f(uint32_t u) {
  union { float f; uint32_t i; } x; x.i = u << 16; return x.f;
}
__device__ __forceinline__ unsigned short bfbits(float f) {
  __hip_bfloat16 h = __float2bfloat16(f);
  return *(unsigned short*)&h;
}
__device__ __forceinline__ uint32_t splitbf(float f) {
  unsigned short hi = bfbits(f);
  union { uint32_t u; float ff; } c; c.u = (uint32_t)hi << 16;
  unsigned short lo = bfbits(f - c.ff);
  return (uint32_t)hi | ((uint32_t)lo << 16);
}
__device__ __forceinline__ float sigm(float x) { return 1.f / (1.f + __expf(-x)); }

__device__ __forceinline__ void stg(float* p, float v) {
  __hip_atomic_store(p, v, __ATOMIC_RELAXED, __HIP_MEMORY_SCOPE_AGENT);
}
__device__ __forceinline__ void stgu(uint32_t* p, uint32_t v) {
  __hip_atomic_store(p, v, __ATOMIC_RELAXED, __HIP_MEMORY_SCOPE_AGENT);
}
__device__ __forceinline__ void stgi(int* p, int v) {
  __hip_atomic_store(p, v, __ATOMIC_RELAXED, __HIP_MEMORY_SCOPE_AGENT);
}
__device__ __forceinline__ void stg64(unsigned long long* p, unsigned long long v) {
  __hip_atomic_store(p, v, __ATOMIC_RELAXED, __HIP_MEMORY_SCOPE_AGENT);
}
__device__ __forceinline__ float ldg1(const float* p) {
  return __hip_atomic_load((float*)p, __ATOMIC_RELAXED, __HIP_MEMORY_SCOPE_AGENT);
}
__device__ __forceinline__ int ldgi(const int* p) {
  return __hip_atomic_load((int*)p, __ATOMIC_RELAXED, __HIP_MEMORY_SCOPE_AGENT);
}
__device__ __forceinline__ unsigned long long ldg8(const void* p) {
  return __hip_atomic_load((unsigned long long*)p, __ATOMIC_RELAXED, __HIP_MEMORY_SCOPE_AGENT);
}

#define POLL_GE(addr, thr) \
  while (ldgi(addr) < (thr)) __builtin_amdgcn_s_sleep(1);
#define CFENCE() __asm__ __volatile__("" ::: "memory")

__global__ __launch_bounds__(256) void k0_prep(
    const float* __restrict__ aiw, const float* __restrict__ aib,
    const float* __restrict__ aow, const float* __restrict__ aob,
    const float* __restrict__ outw, const float* __restrict__ lng,
    const float* __restrict__ lnb, char* __restrict__ ws) {
  float* Gm = (float*)(ws + OFF_G);
  float* Nm = (float*)(ws + OFF_NM);
  float* m0 = (float*)(ws + OFF_M0);
  float* n0 = (float*)(ws + OFF_N0);
  float* wqb = (float*)(ws + OFF_WQB);
  float* sc = (float*)(ws + OFF_SC);
  const int blk = blockIdx.x, tid = threadIdx.x;
  if (blk == 512) {
    uint32_t* hb = (uint32_t*)(ws + OFF_HB);
    int* fl = (int*)(ws + OFF_FLG);
    unsigned long long* xpk = (unsigned long long*)(ws + OFF_XPK);
    for (int i = tid; i < 3*NBAT*HID; i += 256) hb[i] = 0u;          // all 3 slots zeroed
    for (int i = tid; i < 3*NGRP*GBLK*FLS; i += 256) fl[i] = 0;      // replay-safe
    for (int i = tid; i < NBAT; i += 256) xpk[i] = 0ull;
    for (int l = tid; l < HID; l += 256) {
      float s = 0.f;
      for (int i = 0; i < HID; i++) s += aib[i] * aiw[(size_t)(HID + i)*HID + l];
      m0[l] = s;  // Wk^T bq
    }
    for (int l = tid; l < HID; l += 256) {
      float s = 0.f;
      for (int i = 0; i < HID; i++) s += aiw[(size_t)i*HID + l] * aib[HID + i];
      wqb[l] = s;  // Wq^T bk
    }
    for (int j = tid; j < HID; j += 256) {
      float s = aob[j];
      for (int i = 0; i < HID; i++) s += aow[(size_t)j*HID + i] * aib[2*HID + i];
      n0[j] = s;  // aow*bv + aob
    }
    __shared__ float red[256];
    float a = 0.f, b = 0.f, d = 0.f;
    for (int l = tid; l < HID; l += 256) {
      a += outw[l]*lng[l]; b += outw[l]*lnb[l]; d += aib[l]*aib[HID + l];
    }
    red[tid] = a; __syncthreads();
    for (int st = 128; st; st >>= 1) { if (tid < st) red[tid] += red[tid + st]; __syncthreads(); }
    if (tid == 0) sc[0] = red[0];
    __syncthreads();
    red[tid] = b; __syncthreads();
    for (int st = 128; st; st >>= 1) { if (tid < st) red[tid] += red[tid + st]; __syncthreads(); }
    if (tid == 0) sc[1] = red[0];
    __syncthreads();
    red[tid] = d; __syncthreads();
    for (int st = 128; st; st >>= 1) { if (tid < st) red[tid] += red[tid + st]; __syncthreads(); }
    if (tid == 0) sc[2] = red[0];  // bq.bk
    return;
  }
  const bool isG = blk < 256;
  const int tb = isG ? blk : blk - 256;
  const int r0 = (tb >> 4) * 32, c0 = (tb & 15) * 32;
  __shared__ float sa[32][33], sb[32][33];
  float acc[4] = {0.f, 0.f, 0.f, 0.f};
  const int tr = tid >> 3, tc = (tid & 7) * 4;
  for (int i0 = 0; i0 < HID; i0 += 32) {
    __syncthreads();
    if (isG) {  // Gm[l][k] = sum_i Wk[i][l]*Wq[i][k]
      for (int j = 0; j < 4; j++) sa[tr][tc + j] = aiw[(size_t)(HID + i0 + tr)*HID + r0 + tc + j];
      for (int j = 0; j < 4; j++) sb[tr][tc + j] = aiw[(size_t)(i0 + tr)*HID + c0 + tc + j];
    } else {    // N[j][l] = sum_i aow[j][i]*Wv[i][l]
      for (int j = 0; j < 4; j++) sa[tr][tc + j] = aow[(size_t)(r0 + tr)*HID + i0 + tc + j];
      for (int j = 0; j < 4; j++) sb[tr][tc + j] = aiw[(size_t)(2*HID + i0 + tr)*HID + c0 + tc + j];
    }
    __syncthreads();
    if (isG) {
      for (int i = 0; i < 32; i++) {
        float a = sa[i][tr];
        for (int j = 0; j < 4; j++) acc[j] += a * sb[i][tc + j];
      }
    } else {
      for (int i = 0; i < 32; i++) {
        float a = sa[tr][i];
        for (int j = 0; j < 4; j++) acc[j] += a * sb[i][tc + j];
      }
    }
  }
  float* dst = isG ? Gm : Nm;
  for (int j = 0; j < 4; j++) dst[(size_t)(r0 + tr)*HID + c0 + tc + j] = acc[j];
}

// B-fragments (verified)
__global__ __launch_bounds__(256) void k0b_frag(char* __restrict__ ws) {
  const float* Gm = (const float*)(ws + OFF_G);
  const float* Nm = (const float*)(ws + OFF_NM);
  unsigned short* Bfk = (unsigned short*)(ws + OFF_BFK);
  unsigned short* Bfv = (unsigned short*)(ws + OFF_BFV);
  const int idx0 = blockIdx.x * 256 + threadIdx.x;
  for (int idx = idx0; idx < 16*32*64; idx += 64*256) {
    int ks = idx >> 11, lt = (idx >> 6) & 31, l = idx & 63;
    int lcol = lt*16 + (l & 15), krow = ks*32 + ((l >> 4) << 3);
    unsigned short hk[8] __attribute__((aligned(16)));
    unsigned short hv[8] __attribute__((aligned(16)));
    for (int j = 0; j < 8; j++) {
      hk[j] = bfbits(Gm[(size_t)(krow + j)*HID + lcol]);
      hv[j] = bfbits(Nm[(size_t)lcol*HID + krow + j]);
    }
    *(uint4*)(Bfk + (size_t)idx*8) = *(uint4*)hk;
    *(uint4*)(Bfv + (size_t)idx*8) = *(uint4*)hv;
  }
}

// full-tile stage, 512 threads (k2 preloop)
#define STAGE_FULL8(srcPTR)                                                           \
  {                                                                                   \
    const unsigned long long* _s = (const unsigned long long*)(srcPTR);               \
    unsigned long long _tm[8];                                                        \
    _Pragma("unroll") for (int r = 0; r < 8; r++) _tm[r] = ldg8(_s + tid + r*512);    \
    _Pragma("unroll") for (int r = 0; r < 8; r++) {                                   \
      int i = tid + r*512;                                                            \
      int bb_ = i >> 8, kk = (i & 255) * 2;                                           \
      unsigned long long u = _tm[r];                                                  \
      *(uint32_t*)&s_hh[bb_][kk] = (uint32_t)(u & 0xffffu) | (((uint32_t)(u >> 32) & 0xffffu) << 16); \
      *(uint32_t*)&s_hl[bb_][kk] = ((uint32_t)(u >> 16) & 0xffffu) | ((uint32_t)(u >> 48) << 16);     \
    }                                                                                 \
  }

// per-wave slice stage (8 waves): wave wv stages u64 cols [wv*32,+32) all 16 batches.
#define STAGE_SLICE8(srcPTR)                                                          \
  {                                                                                   \
    const unsigned long long* _s = (const unsigned long long*)(srcPTR);               \
    const int _half = l >> 5, _co = wv*32 + (l & 31);                                 \
    unsigned long long _tm[8];                                                        \
    _Pragma("unroll") for (int r = 0; r < 8; r++)                                     \
      _tm[r] = ldg8(_s + (size_t)(_half*8 + r)*(HID/2) + _co);                        \
    const int kk = _co*2;                                                             \
    _Pragma("unroll") for (int r = 0; r < 8; r++) {                                   \
      unsigned long long u = _tm[r];                                                  \
      int bb_ = _half*8 + r;                                                          \
      *(uint32_t*)&s_hh[bb_][kk] = (uint32_t)(u & 0xffffu) | (((uint32_t)(u >> 32) & 0xffffu) << 16); \
      *(uint32_t*)&s_hl[bb_][kk] = ((uint32_t)(u >> 16) & 0xffffu) | ((uint32_t)(u >> 48) << 16);     \
    }                                                                                 \
  }

#define WFRAG_INIT_512()                                                              \
  for (int slot = tid; slot < 2*16*64; slot += 512) {                                 \
    int T = slot >> 10, ks = (slot >> 6) & 15, l_ = slot & 63;                        \
    int rloc = T*16 + (l_ & 15);                                                      \
    int grow = (rloc >> 3)*HID + hs + (rloc & 7);                                     \
    int ko = ks*32 + ((l_ >> 4) << 3);                                                \
    const float* wp = &whh[(size_t)grow*HID + ko];                                    \
    unsigned short hi[8] __attribute__((aligned(16)));                                \
    unsigned short lo[8] __attribute__((aligned(16)));                                \
    for (int j = 0; j < 8; j++) {                                                     \
      uint32_t u = splitbf(wp[j]);                                                    \
      hi[j] = (unsigned short)u; lo[j] = (unsigned short)(u >> 16);                   \
    }                                                                                 \
    *(uint4*)&s_wf[T][ks][l_][0] = *(uint4*)hi;                                       \
    *(uint4*)&s_wl[T][ks][l_][0] = *(uint4*)lo;                                       \
  }

// 8-wave cell MFMA, LDS weights (k1): wave wv does ks = wv*2, wv*2+1
#define CELL_MFMA8()                                                                  \
  {                                                                                   \
    f32x4 acc0 = {0.f,0.f,0.f,0.f}, acc1 = {0.f,0.f,0.f,0.f};                         \
    _Pragma("unroll") for (int kq = 0; kq < 2; kq++) {                                \
      const int ks = wv*2 + kq;                                                       \
      const int ko = ks*32 + (oc << 3);                                               \
      bf16x8 ahi = *(const bf16x8*)&s_hh[lm][ko];                                     \
      bf16x8 alo = *(const bf16x8*)&s_hl[lm][ko];                                     \
      bf16x8 b0h = *(const bf16x8*)&s_wf[0][ks][l][0];                                \
      bf16x8 b0l = *(const bf16x8*)&s_wl[0][ks][l][0];                                \
      bf16x8 b1h = *(const bf16x8*)&s_wf[1][ks][l][0];                                \
      bf16x8 b1l = *(const bf16x8*)&s_wl[1][ks][l][0];                                \
      acc0 = MFMA_B16(ahi, b0h, acc0, 0, 0, 0);                                       \
      acc0 = MFMA_B16(alo, b0h, acc0, 0, 0, 0);                                       \
      acc0 = MFMA_B16(ahi, b0l, acc0, 0, 0, 0);                                       \
      acc1 = MFMA_B16(ahi, b1h, acc1, 0, 0, 0);                                       \
      acc1 = MFMA_B16(alo, b1h, acc1, 0, 0, 0);                                       \
      acc1 = MFMA_B16(ahi, b1l, acc1, 0, 0, 0);                                       \
    }                                                                                 \
    _Pragma("unroll") for (int q = 0; q < 4; q++) {                                   \
      int idx = (oc*4 + q)*16 + lm;                                                   \
      s_pacc[wv][0][idx] = acc0[q];                                                   \
      s_pacc[wv][1][idx] = acc1[q];                                                   \
    }                                                                                 \
  }                                                                                   \
  __syncthreads();

// 8-wave cell MFMA, register weights (k2)
#define CELL_MFMA8R()                                                                 \
  {                                                                                   \
    f32x4 acc0 = {0.f,0.f,0.f,0.f}, acc1 = {0.f,0.f,0.f,0.f};                         \
    _Pragma("unroll") for (int kq = 0; kq < 2; kq++) {                                \
      const int ks = wv*2 + kq;                                                       \
      const int ko = ks*32 + (oc << 3);                                               \
      bf16x8 ahi = *(const bf16x8*)&s_hh[lm][ko];                                     \
      bf16x8 alo = *(const bf16x8*)&s_hl[lm][ko];                                     \
      acc0 = MFMA_B16(ahi, wh0[kq], acc0, 0, 0, 0);                                   \
      acc0 = MFMA_B16(alo, wh0[kq], acc0, 0, 0, 0);                                   \
      acc0 = MFMA_B16(ahi, wl0[kq], acc0, 0, 0, 0);                                   \
      acc1 = MFMA_B16(ahi, wh1[kq], acc1, 0, 0, 0);                                   \
      acc1 = MFMA_B16(alo, wh1[kq], acc1, 0, 0, 0);                                   \
      acc1 = MFMA_B16(ahi, wl1[kq], acc1, 0, 0, 0);                                   \
    }                                                                                 \
    _Pragma("unroll") for (int q = 0; q < 4; q++) {                                   \
      int idx = (oc*4 + q)*16 + lm;                                                   \
      s_pacc[wv][0][idx] = acc0[q];                                                   \
      s_pacc[wv][1][idx] = acc1[q];                                                   \
    }                                                                                 \
  }                                                                                   \
  __syncthreads();

#define GATES_SUM()                                                                   \
      float zi = 0.f, zf = 0.f, zg = 0.f, zo = 0.f;                                   \
      _Pragma("unroll") for (int w = 0; w < 8; w++) {                                 \
        zi += s_pacc[w][0][b*16+j];                                                   \
        zf += s_pacc[w][0][b*16+8+j];                                                 \
        zg += s_pacc[w][1][b*16+j];                                                   \
        zo += s_pacc[w][1][b*16+8+j];                                                 \
      }                                                                               \
      float x = s_x[b];                                                               \
      zi += x*s_wih[j]    + s_bias[j];                                                \
      zf += x*s_wih[8+j]  + s_bias[8+j];                                              \
      zg += x*s_wih[16+j] + s_bias[16+j];                                             \
      zo += x*s_wih[24+j] + s_bias[24+j];

__global__ __launch_bounds__(512) void k1_enc(
    const float* __restrict__ xin, const float* __restrict__ wih,
    const float* __restrict__ whh, const float* __restrict__ bih,
    const float* __restrict__ bhh, char* __restrict__ ws) {
  const int bk = blockIdx.x, tid = threadIdx.x;
  const int g = bk >> 6, jb = bk & 63;
  const int hs = jb * NH, b0 = g * GBAT;
  uint32_t* hbuf = (uint32_t*)(ws + OFF_HB);
  float* cbuf = (float*)(ws + OFF_CB);
  unsigned short* eo = (unsigned short*)(ws + OFF_EO);
  int* fl = (int*)(ws + OFF_FLG) + g * GBLK * FLS;

  __shared__ __align__(16) unsigned short s_wf[2][16][64][8];
  __shared__ __align__(16) unsigned short s_wl[2][16][64][8];
  __shared__ __align__(16) unsigned short s_hh[GBAT][520];
  __shared__ __align__(16) unsigned short s_hl[GBAT][520];
  __shared__ float s_pacc[8][2][256];
  __shared__ float s_c[GBAT][NH];
  __shared__ float s_x[GBAT];
  __shared__ float s_wih[32], s_bias[32];

  WFRAG_INIT_512()
  if (tid < 32) {
    int grow = (tid >> 3)*HID + hs + (tid & 7);
    s_wih[tid] = wih[grow];
    s_bias[tid] = bih[grow] + bhh[grow];
  }
  for (int i = tid; i < GBAT*NH; i += 512) s_c[i >> 3][i & 7] = 0.f;
  __syncthreads();   // init LDS (weights, biases, c) visible before first CELL

  const int l = tid & 63, wv = tid >> 6;
  const int lm = l & 15, oc = l >> 4;

  for (int t = 0; t < SEQE; t++) {
    if (tid < GBAT) s_x[tid] = xin[(size_t)(b0 + tid)*SEQE + t];
    // wave-local wait: my 8 h-producers stored h_t. Collectively (8 waves x 8)
    // ALL 64 flags checked >= t, barrier-ordered before the h(t+1) store below.
    if (l < 8) { POLL_GE(&fl[(wv*8 + l)*FLS], t) }
    CFENCE();
    STAGE_SLICE8(hbuf + (size_t)(t % 3)*NBAT*HID + (size_t)b0*HID)
    CELL_MFMA8()   // trailing syncthreads: s_pacc ready AND all polls passed
    if (tid < 128) {
      int b = tid >> 3, j = tid & 7;
      GATES_SUM()
      float c = s_c[b][j];
      c = sigm(zf)*c + sigm(zi)*tanhf(zg);
      float hv = sigm(zo)*tanhf(c);
      s_c[b][j] = c;
      uint32_t pk = splitbf(hv);
      stgu(&hbuf[(size_t)((t+1)%3)*NBAT*HID + (size_t)(b0+b)*HID + hs + j], pk);
      eo[((size_t)(b0+b)*SEQE + t)*HID + hs + j] = (unsigned short)(pk & 0xffffu);
    }
    __syncthreads();  // drains vmcnt: h stores at coherence point before flag
    if (tid == 0) stgi(&fl[jb*FLS], t + 1);
  }
  __syncthreads();   // final s_c updates visible to all
  if (tid < GBAT*NH)
    cbuf[(size_t)(b0 + (tid >> 3))*HID + hs + (tid & 7)] = s_c[tid >> 3][tid & 7];
}

// K~/V~ precompute (R5-verified, unchanged)
__global__ __launch_bounds__(256) void k0c_kv(char* __restrict__ ws) {
  const float* wqb = (const float*)(ws + OFF_WQB);
  const float* m0 = (const float*)(ws + OFF_M0);
  const float* scv = (const float*)(ws + OFF_SC);
  const unsigned short* Bfk = (const unsigned short*)(ws + OFF_BFK);
  const unsigned short* Bfv = (const unsigned short*)(ws + OFF_BFV);
  unsigned short* eoK = (unsigned short*)(ws + OFF_EO);
  unsigned short* Vt = (unsigned short*)(ws + OFF_VT);
  float* kbv = (float*)(ws + OFF_KB);
  const int b = blockIdx.x >> 4, s0 = (blockIdx.x & 15) * 32;
  const int tid = threadIdx.x;
  __shared__ __align__(16) unsigned short s_e[32][520];
  __shared__ float s_kb[32][8];
  {
    const uint4* src = (const uint4*)(eoK + ((size_t)b*SEQE + s0)*HID);
    #pragma unroll
    for (int r = 0; r < 8; r++) {
      int i = tid + r*256;
      uint4 v = src[i];
      int rr = i >> 6, cc = (i & 63)*8;
      *(uint4*)&s_e[rr][cc] = v;
    }
  }
  __syncthreads();
  const int l = tid & 63, wv = tid >> 6, lm = l & 15, oc = l >> 4;
  for (int nt = 0; nt < 8; nt++) {
    const int lt = wv*8 + nt;
    f32x4 accK0 = {0,0,0,0}, accK1 = {0,0,0,0}, accV0 = {0,0,0,0}, accV1 = {0,0,0,0};
    #pragma unroll
    for (int ks = 0; ks < 16; ks++) {
      bf16x8 yk = *(const bf16x8*)(Bfk + (((size_t)ks*32 + lt)*64 + l)*8);
      bf16x8 yv = *(const bf16x8*)(Bfv + (((size_t)ks*32 + lt)*64 + l)*8);
      bf16x8 xe0 = *(const bf16x8*)&s_e[lm][ks*32 + oc*8];
      bf16x8 xe1 = *(const bf16x8*)&s_e[16 + lm][ks*32 + oc*8];
      accK0 = MFMA_B16(xe0, yk, accK0, 0,0,0);
      accK1 = MFMA_B16(xe1, yk, accK1, 0,0,0);
      accV0 = MFMA_B16(xe0, yv, accV0, 0,0,0);
      accV1 = MFMA_B16(xe1, yv, accV1, 0,0,0);
    }
    const float wq = wqb[lt*16 + lm];
    #pragma unroll
    for (int st = 0; st < 2; st++) {
      const f32x4& aK = st ? accK1 : accK0;
      const f32x4& aV = st ? accV1 : accV0;
      #pragma unroll
      for (int q = 0; q < 4; q++)
        eoK[((size_t)b*SEQE + s0 + st*16 + oc*4 + q)*HID + lt*16 + lm] = bfbits(aK[q] + wq);
      unsigned short pv[4] __attribute__((aligned(8)));
      #pragma unroll
      for (int q = 0; q < 4; q++) pv[q] = bfbits(aV[q]);
      *(unsigned long long*)(Vt + ((size_t)b*HID + lt*16 + lm)*SEQE + s0 + st*16 + oc*4)
          = *(unsigned long long*)pv;
    }
  }
  {
    int s = tid >> 3, kc = tid & 7;
    float acc = 0.f;
    for (int i = 0; i < 64; i++) {
      int k = kc*64 + i;
      acc += bf2f((uint32_t)s_e[s][k]) * m0[k];
    }
    s_kb[s][kc] = acc;
  }
  __syncthreads();
  if (tid < 32) {
    float a = 0.f;
    for (int kc = 0; kc < 8; kc++) a += s_kb[tid][kc];
    kbv[(size_t)b*SEQE + s0 + tid] = a + scv[2];
  }
}

__global__ __launch_bounds__(512) void k2_dec(
    const float* __restrict__ xin, const float* __restrict__ wih,
    const float* __restrict__ whh, const float* __restrict__ bih,
    const float* __restrict__ bhh, const float* __restrict__ lng,
    const float* __restrict__ lnb, const float* __restrict__ outw,
    const float* __restrict__ outb, char* __restrict__ ws,
    float* __restrict__ dout) {
  const int bk = blockIdx.x, tid = threadIdx.x;
  const int g = bk >> 6, jb = bk & 63;
  const int hs = jb * NH, b0 = g * GBAT;
  uint32_t* hbuf = (uint32_t*)(ws + OFF_HB);
  float* cbuf = (float*)(ws + OFF_CB);
  float* ebp  = (float*)(ws + OFF_EBP);
  float* md   = (float*)(ws + OFF_MD);
  const float* n0v = (const float*)(ws + OFF_N0);
  const float* scv = (const float*)(ws + OFF_SC);
  const float* kbv = (const float*)(ws + OFF_KB);
  const unsigned short* Kt = (const unsigned short*)(ws + OFF_EO);
  const unsigned short* Vt = (const unsigned short*)(ws + OFF_VT);
  unsigned long long* xpk = (unsigned long long*)(ws + OFF_XPK);
  int* fl2 = (int*)(ws + OFF_FLG) + (NGRP + g) * GBLK * FLS;
  int* pfl = (int*)(ws + OFF_FLG) + (2*NGRP + g) * GBLK * FLS;

  __shared__ __align__(16) unsigned short s_hh[GBAT][520];
  __shared__ __align__(16) unsigned short s_hl[GBAT][520];
  __shared__ __align__(16) unsigned short s_kt[64][520];  // K~ rows 0-63 pinned
  __shared__ float s_pacc[8][2][256];
  __shared__ float s_own[HID];      // own-chunk PV partials (used by scq==0 blocks)
  __shared__ float s_d0;            // own-chunk denominator
  __shared__ float s_c[GBAT][NH];
  __shared__ float s_x[GBAT];
  __shared__ float s_wih[32], s_bias[32];
  __shared__ float s_scores[128];
  __shared__ __align__(16) uint32_t s_pbf[64];
  __shared__ float s_red[32];
  __shared__ float s_ln[HID], s_n0f[HID];

  const int l = tid & 63, wv = tid >> 6;
  const int lm = l & 15, oc = l >> 4;
  const int bb = jb >> 2, scq = jb & 3, batch = b0 + bb;

  // cell weights -> registers (split-bf16 B-fragments)
  bf16x8 wh0[2], wl0[2], wh1[2], wl1[2];
  #pragma unroll
  for (int kq = 0; kq < 2; kq++) {
    const int ks = wv*2 + kq;
    #pragma unroll
    for (int T = 0; T < 2; T++) {
      int rloc = T*16 + lm;
      int grow = (rloc >> 3)*HID + hs + (rloc & 7);
      const float* wp = &whh[(size_t)grow*HID + ks*32 + oc*8];
      unsigned short hi8[8] __attribute__((aligned(16)));
      unsigned short lo8[8] __attribute__((aligned(16)));
      #pragma unroll
      for (int j = 0; j < 8; j++) {
        uint32_t u = splitbf(wp[j]);
        hi8[j] = (unsigned short)u; lo8[j] = (unsigned short)(u >> 16);
      }
      if (T == 0) { wh0[kq] = *(bf16x8*)hi8; wl0[kq] = *(bf16x8*)lo8; }
      else        { wh1[kq] = *(bf16x8*)hi8; wl1[kq] = *(bf16x8*)lo8; }
    }
  }
  // V~ slice -> registers (loop-invariant)
  bf16x8 vreg[4][4];
  {
    const unsigned short* vp = Vt + (size_t)batch*HID*SEQE + (size_t)scq*128;
    #pragma unroll
    for (int n = 0; n < 4; n++)
      #pragma unroll
      for (int ks = 0; ks < 4; ks++)
        vreg[n][ks] = *(const bf16x8*)(vp + (size_t)((wv*4 + n)*16 + lm)*SEQE + ks*32 + oc*8);
  }
  // K~ rows 0-63 -> LDS (loop-invariant)
  for (int i = tid; i < 4096; i += 512) {
    int row = i >> 6, cc = (i & 63) * 8;
    *(uint4*)&s_kt[row][cc] =
        *(const uint4*)(Kt + ((size_t)batch*SEQE + scq*128 + row)*HID + cc);
  }
  if (tid < 32) {
    int grow = (tid >> 3)*HID + hs + (tid & 7);
    s_wih[tid] = wih[grow];
    s_bias[tid] = bih[grow] + bhh[grow];
  }
  for (int i = tid; i < HID; i += 512) {
    s_ln[i] = outw[i] * lng[i];
    s_n0f[i] = n0v[i];
  }
  for (int i = tid; i < GBAT*NH; i += 512)
    s_c[i >> 3][i & 7] = cbuf[(size_t)(b0 + (i >> 3))*HID + hs + (i & 7)];
  const float Swg = scv[0], Swb = scv[1], ob0 = outb[0];

  // preloop: h_e lives in slot SEQE%3 == 2 (k1's final store, u32 format)
  STAGE_FULL8(hbuf + (size_t)2*NBAT*HID + (size_t)b0*HID)
  if (tid < GBAT) s_x[tid] = xin[(size_t)(b0 + tid)*SEQD];
  __syncthreads();

  for (int t = 0; t < SEQD; t++) {
    // ---- cell: h(t+1) from s_hh (h(t)). Overlaps P3(t-1)->xpk chain. ----
    CELL_MFMA8R()   // trailing syncthreads
    // ---- x-wait for x(t) (epoch t), moved here from loop tail (R13).
    // Safety: xpk overwrite to epoch t+1 requires quad's stage(t) -> fl2>=t+1
    // from ALL 64 -> every block's gates(t) -> its x-wait(t) read done. ----
    if (t > 0) {
      if (tid < GBAT) {
        unsigned long long v;
        do { v = ldg8(&xpk[b0 + tid]); __builtin_amdgcn_s_sleep(1); }
        while ((uint32_t)v < (uint32_t)t);
        union { uint32_t u; float f; } cv; cv.u = (uint32_t)(v >> 32);
        s_x[tid] = cv.f;
      }
      __syncthreads();
    }
    if (tid < 128) {
      int b = tid >> 3, j = tid & 7;
      GATES_SUM()
      float c = s_c[b][j];
      c = sigm(zf)*c + sigm(zi)*tanhf(zg);
      float hv = sigm(zo)*tanhf(c);
      s_c[b][j] = c;
      stgu(&hbuf[(size_t)((t+1)%3)*NBAT*HID + (size_t)(b0+b)*HID + hs + j], splitbf(hv));
    }
    __syncthreads();          // drains vmcnt before flag
    if (tid == 0) stgi(&fl2[jb*FLS], t + 1);
    // ---- stage h(t+1) (per-wave, 8-producer wait; 8x8 = all 64 checked) ----
    if (l < 8) { POLL_GE(&fl2[(wv*8 + l)*FLS], t + 1) }
    CFENCE();
    STAGE_SLICE8(hbuf + (size_t)((t+1)%3)*NBAT*HID + (size_t)b0*HID)
    __syncthreads();          // full h(t+1) row available
    // ---- scores: waves 0-3 LDS-pinned K~, waves 4-7 streamed (L2-resident) ----
    {
      f32x4 acc = {0.f,0.f,0.f,0.f};
      if (wv < 4) {
        #pragma unroll
        for (int ks = 0; ks < 16; ks++) {
          bf16x8 xh = *(const bf16x8*)&s_hh[bb][ks*32 + oc*8];
          bf16x8 yk = *(const bf16x8*)&s_kt[wv*16 + lm][ks*32 + oc*8];
          acc = MFMA_B16(xh, yk, acc, 0, 0, 0);
        }
      } else {
        const unsigned short* kp =
            Kt + ((size_t)batch*SEQE + scq*128 + 64 + (wv - 4)*16)*HID;
        #pragma unroll
        for (int ks = 0; ks < 16; ks++) {
          bf16x8 xh = *(const bf16x8*)&s_hh[bb][ks*32 + oc*8];
          bf16x8 yk = *(const bf16x8*)(kp + (size_t)lm*HID + ks*32 + oc*8);
          acc = MFMA_B16(xh, yk, acc, 0, 0, 0);
        }
      }
      if (oc == 0) s_scores[wv*16 + lm] = acc[0];
    }
    __syncthreads();
    float den_part = 0.f;
    if (tid < 128) {
      float sv = (s_scores[tid] + kbv[(size_t)batch*SEQE + scq*128 + tid]) * SCALE;
      den_part = __expf(sv);
      s_scores[tid] = den_part;
    }
    __syncthreads();
    if (tid < 64)
      s_pbf[tid] = (uint32_t)bfbits(s_scores[2*tid]) | ((uint32_t)bfbits(s_scores[2*tid+1]) << 16);
    if (tid < 128) {
      for (int off = 32; off; off >>= 1) den_part += __shfl_down(den_part, off);
      if ((tid & 63) == 0) s_red[tid >> 6] = den_part;
    }
    __syncthreads();
    if (tid == 0) {
      float den = s_red[0] + s_red[1];
      stg(&md[batch*4 + scq], den);
      s_d0 = den;               // local copy for own-chunk P3 shortcut
    }
    // ---- PV from registers (+ own-chunk LDS copy) ----
    {
      #pragma unroll
      for (int n = 0; n < 4; n++) {
        const int lv0 = (wv*4 + n)*16;
        f32x4 acc = {0.f,0.f,0.f,0.f};
        #pragma unroll
        for (int ks = 0; ks < 4; ks++) {
          bf16x8 xp = *(const bf16x8*)((const unsigned short*)s_pbf + ks*32 + oc*8);
          acc = MFMA_B16(xp, vreg[n][ks], acc, 0, 0, 0);
        }
        if (oc == 0) {
          stg(&ebp[((size_t)batch*4 + scq)*HID + lv0 + lm], acc[0]);
          s_own[lv0 + lm] = acc[0];
        }
      }
    }
    __syncthreads();          // drains vmcnt: ebp/md stores at coherence point
    if (tid == 0) stgi(&pfl[jb*FLS], t + 1);
    // ---- P3 (scq==0 blocks, own batch): combine + LN + out + x publish ----
    if (scq == 0) {
      const int mb = batch;   // = b0 + bb
      #pragma unroll
      for (int q = 1; q < 4; q++) { POLL_GE(&pfl[(4*bb + q)*FLS], t + 1) }
      CFENCE();
      if (tid < 3) s_red[tid] = ldg1(&md[mb*4 + 1 + tid]);
      __syncthreads();
      const float inv = 1.f / (s_d0 + s_red[0] + s_red[1] + s_red[2]);
      if (tid < 256) {
        float sy = 0.f, sy2 = 0.f, sg = 0.f;
        #pragma unroll
        for (int u = 0; u < 2; u++) {
          const int lv = tid*2 + u;
          float p0 = s_own[lv];
          float p1 = ldg1(&ebp[((size_t)mb*4 + 1)*HID + lv]);
          float p2 = ldg1(&ebp[((size_t)mb*4 + 2)*HID + lv]);
          float p3 = ldg1(&ebp[((size_t)mb*4 + 3)*HID + lv]);
          float hval = bf2f((uint32_t)s_hh[bb][lv]) + bf2f((uint32_t)s_hl[bb][lv]);
          float y = (p0 + p1 + p2 + p3)*inv + s_n0f[lv] + hval;
          sy += y; sy2 += y*y; sg += s_ln[lv]*y;
        }
        for (int off = 32; off; off >>= 1) {
          sy += __shfl_down(sy, off); sy2 += __shfl_down(sy2, off); sg += __shfl_down(sg, off);
        }
        if (l == 0) { s_red[8+wv] = sy; s_red[12+wv] = sy2; s_red[16+wv] = sg; }
      }
      __syncthreads();
      if (tid == 0) {
        float Sy  = s_red[8]  + s_red[9]  + s_red[10] + s_red[11];
        float Sy2 = s_red[12] + s_red[13] + s_red[14] + s_red[15];
        float Sg  = s_red[16] + s_red[17] + s_red[18] + s_red[19];
        float mu = Sy * (1.f/HID);
        float var = Sy2 * (1.f/HID) - mu*mu;
        float rs = rsqrtf(var + 1e-5f);
        float o = rs*(Sg - mu*Swg) + Swb + ob0;
        dout[(size_t)mb*SEQD + t] = o;
        union { float f; uint32_t u; } cv; cv.f = o;
        stg64(&xpk[mb], ((unsigned long long)cv.u << 32) | (uint32_t)(t + 1));
      }
    }
    // (x-wait for epoch t+1 happens at top of next iteration, after CELL)
  }
}

extern "C" void kernel_launch(void* const* d_in, const int* in_sizes, int n_in,
                              void* d_out, int out_size, void* d_ws, size_t ws_size,
                              hipStream_t stream) {
  const float* enc_in = (const float*)d_in[0];
  const float* dec_in = (const float*)d_in[1];
  const float* ewih = (const float*)d_in[2];
  const float* ewhh = (const float*)d_in[3];
  const float* ebih = (const float*)d_in[4];
  const float* ebhh = (const float*)d_in[5];
  const float* dwih = (const float*)d_in[6];
  const float* dwhh = (const float*)d_in[7];
  const float* dbih = (const float*)d_in[8];
  const float* dbhh = (const float*)d_in[9];
  const float* aiw  = (const float*)d_in[10];
  const float* aib  = (const float*)d_in[11];
  const float* aow  = (const float*)d_in[12];
  const float* aob  = (const float*)d_in[13];
  const float* lng  = (const float*)d_in[14];
  const float* lnb  = (const float*)d_in[15];
  const float* outw = (const float*)d_in[16];
  const float* outb = (const float*)d_in[17];
  char* ws = (char*)d_ws;
  k0_prep<<<513, 256, 0, stream>>>(aiw, aib, aow, aob, outw, lng, lnb, ws);
  k0b_frag<<<64, 256, 0, stream>>>(ws);
  k1_enc<<<256, 512, 0, stream>>>(enc_in, ewih, ewhh, ebih, ebhh, ws);
  k0c_kv<<<1024, 256, 0, stream>>>(ws);
  k2_dec<<<256, 512, 0, stream>>>(dec_in, dwih, dwhh, dbih, dbhh,
                                  lng, lnb, outw, outb, ws, (float*)d_out);
}